// Round 1
// baseline (736.425 us; speedup 1.0000x reference)
//
#include <hip/hip_runtime.h>

typedef unsigned short ushort_t;
using short8  = __attribute__((ext_vector_type(8))) short;
using floatx4 = __attribute__((ext_vector_type(4))) float;

__device__ __forceinline__ ushort_t f2bf(float f) {
  unsigned int x = __builtin_bit_cast(unsigned int, f);
  x += 0x7fffu + ((x >> 16) & 1u);           // RNE
  return (ushort_t)(x >> 16);
}

__device__ __forceinline__ void gld16(const ushort_t* g, ushort_t* l) {
  __builtin_amdgcn_global_load_lds(
      (const __attribute__((address_space(1))) void*)(unsigned long long)(uintptr_t)g,
      (__attribute__((address_space(3))) void*)l, 16, 0, 0);
}

// C(128x128) = A(128xK, row-major, lda) @ B  where BT is (128 rows of N) x K row-major.
// MFMA f32_16x16x32_bf16. 256 threads = 4 waves in 2x2; each wave 64x64 = 4x4 frags.
template <typename F>
__device__ __forceinline__ void gemm_tile(const ushort_t* __restrict__ A, int lda,
                                          const ushort_t* __restrict__ BT, int ldb,
                                          int K, F epi) {
  __shared__ ushort_t As[128 * 32];
  __shared__ ushort_t Bs[128 * 32];

  const int tid  = threadIdx.x;
  const int wave = tid >> 6;
  const int lane = tid & 63;
  const int l15  = lane & 15;
  const int quad = lane >> 4;
  const int wm   = wave >> 1;
  const int wn   = wave & 1;

  // staging: 4 lanes/row, 16 rows/wave-call, 2 calls -> 32 rows per wave per tile.
  // 16B-chunk xor swizzle: stored chunk c holds global chunk c ^ ((row>>1)&3).
  const int srow   = lane >> 2;
  const int schunk = (lane & 3) ^ ((lane >> 3) & 3);
  const int scol   = schunk * 8;

  const ushort_t* gA0 = A  + (size_t)(wave * 32 + srow) * lda + scol;
  const ushort_t* gA1 = gA0 + (size_t)16 * lda;
  const ushort_t* gB0 = BT + (size_t)(wave * 32 + srow) * ldb + scol;
  const ushort_t* gB1 = gB0 + (size_t)16 * ldb;
  ushort_t* lA0 = As + (wave * 32) * 32;       // wave-uniform LDS bases
  ushort_t* lA1 = As + (wave * 32 + 16) * 32;
  ushort_t* lB0 = Bs + (wave * 32) * 32;
  ushort_t* lB1 = Bs + (wave * 32 + 16) * 32;

  floatx4 acc[4][4] = {};

  // fragment read addresses (swizzled chunk is per-lane constant across i/j)
  const int chunk_sw = quad ^ ((l15 >> 1) & 3);
  const int aoff = (wm * 64 + l15) * 32 + chunk_sw * 8;
  const int boff = (wn * 64 + l15) * 32 + chunk_sw * 8;

  for (int k0 = 0; k0 < K; k0 += 32) {
    gld16(gA0, lA0); gld16(gA1, lA1);
    gld16(gB0, lB0); gld16(gB1, lB1);
    gA0 += 32; gA1 += 32; gB0 += 32; gB1 += 32;
    __syncthreads();                            // drains vmcnt (global_load_lds) too
    short8 af[4], bfr[4];
#pragma unroll
    for (int i = 0; i < 4; i++) af[i]  = *(const short8*)(As + aoff + i * 512);
#pragma unroll
    for (int j = 0; j < 4; j++) bfr[j] = *(const short8*)(Bs + boff + j * 512);
#pragma unroll
    for (int i = 0; i < 4; i++)
#pragma unroll
      for (int j = 0; j < 4; j++)
        acc[i][j] = __builtin_amdgcn_mfma_f32_16x16x32_bf16(af[i], bfr[j], acc[i][j], 0, 0, 0);
    __syncthreads();                            // reads done before next overwrite
  }

#pragma unroll
  for (int i = 0; i < 4; i++)
#pragma unroll
    for (int j = 0; j < 4; j++)
#pragma unroll
      for (int r = 0; r < 4; r++)
        epi(wm * 64 + i * 16 + quad * 4 + r, wn * 64 + j * 16 + l15, acc[i][j][r]);
}

// ---------------- prep kernels ----------------

// adj cast: int32 (B,5,K,K) -> f32 to d_out; slices 1,4 also -> bf16 scratch.
__global__ __launch_bounds__(256) void k_cast(const int* __restrict__ graph,
                                              float* __restrict__ adj_out,
                                              ushort_t* __restrict__ adjb) {
  const size_t i = (size_t)blockIdx.x * 256 + threadIdx.x;   // int4 index
  int4 v = ((const int4*)graph)[i];
  float4 f = make_float4((float)v.x, (float)v.y, (float)v.z, (float)v.w);
  ((float4*)adj_out)[i] = f;
  const size_t e0 = i * 4;
  const unsigned sb = (unsigned)(e0 >> 20);
  const unsigned s = sb % 5u, b = sb / 5u;
  if (s == 1u || s == 4u) {
    const unsigned tt = (s == 4u) ? 1u : 0u;
    ushort4 h;
    h.x = f2bf(f.x); h.y = f2bf(f.y); h.z = f2bf(f.z); h.w = f2bf(f.w);
    *(ushort4*)(adjb + (((size_t)(b * 2 + tt)) << 20) + (e0 & 0xFFFFFu)) = h;
  }
}

__global__ __launch_bounds__(256) void k_castX(const float* __restrict__ gn,
                                               ushort_t* __restrict__ Xb) {
  const size_t i = (size_t)blockIdx.x * 256 + threadIdx.x;
  float4 f = ((const float4*)gn)[i];
  ushort4 h; h.x = f2bf(f.x); h.y = f2bf(f.y); h.z = f2bf(f.z); h.w = f2bf(f.w);
  ((ushort4*)Xb)[i] = h;
}

// W1T[f][d] = Wg1[h][d][ff] (f=h*256+ff);  Wg2bd (256x1024) block-diag of Wg2[h]^T;
// Wf1T/Wf2T plain transposes. All bf16.
__global__ __launch_bounds__(256) void k_prepw(const float* __restrict__ Wg1, const float* __restrict__ Wg2,
                                               const float* __restrict__ Wf1, const float* __restrict__ Wf2,
                                               ushort_t* __restrict__ W1T, ushort_t* __restrict__ Wg2bd,
                                               ushort_t* __restrict__ Wf1T, ushort_t* __restrict__ Wf2T) {
  const int i = blockIdx.x * 256 + threadIdx.x;
  if (i < 262144) {
    const int fI = i >> 8, d = i & 255;
    const int h = fI >> 8, ff = fI & 255;
    W1T[i] = f2bf(Wg1[((h << 8) + d) * 256 + ff]);
  } else if (i < 524288) {
    const int j = i - 262144;
    const int r = j >> 10, c = j & 1023;
    const int h = r >> 6, e = r & 63;
    const float v = ((c >> 8) == h) ? Wg2[((h << 8) + (c & 255)) * 64 + e] : 0.f;
    Wg2bd[j] = f2bf(v);
  } else if (i < 589824) {
    const int j = i - 524288;
    const int n = j >> 8, k = j & 255;
    Wf1T[j] = f2bf(Wf1[k * 256 + n]);
  } else if (i < 655360) {
    const int j = i - 589824;
    const int n = j >> 8, k = j & 255;
    Wf2T[j] = f2bf(Wf2[k * 256 + n]);
  }
}

// ---------------- GEMM step kernels ----------------

// G1: sup1T(1024f x 1024k) = W1T(1024x256) @ X^T   (BT = X (1024k x 256d))
__global__ __launch_bounds__(256) void k_g1(const ushort_t* __restrict__ W1T,
                                            const ushort_t* __restrict__ Xb,
                                            ushort_t* __restrict__ sup1T) {
  const int nt = blockIdx.x, mt = blockIdx.y, b = blockIdx.z;
  const ushort_t* A  = W1T + (size_t)mt * 128 * 256;
  const ushort_t* BT = Xb + (size_t)b * 262144 + (size_t)nt * 128 * 256;
  ushort_t* C = sup1T + ((size_t)b << 20);
  gemm_tile(A, 256, BT, 256, 256, [&](int r, int c, float v) {
    C[(size_t)(mt * 128 + r) * 1024 + nt * 128 + c] = f2bf(v);
  });
}

// G2: h1(1024k x 1024f) = relu(adj_t @ sup1 + bg1); n-tiles 0..3 slice1, 4..7 slice4
__global__ __launch_bounds__(256) void k_g2(const ushort_t* __restrict__ adjb,
                                            const ushort_t* __restrict__ sup1T,
                                            const float* __restrict__ bg1,
                                            ushort_t* __restrict__ h1) {
  const int nt = blockIdx.x, mt = blockIdx.y, b = blockIdx.z;
  const int t = nt >> 2;
  const ushort_t* A  = adjb + ((size_t)(b * 2 + t) << 20) + (size_t)mt * 128 * 1024;
  const ushort_t* BT = sup1T + ((size_t)b << 20) + (size_t)nt * 128 * 1024;
  ushort_t* C = h1 + ((size_t)b << 20);
  const float* bias = bg1 + nt * 128;
  gemm_tile(A, 1024, BT, 1024, 1024, [&](int r, int c, float v) {
    C[(size_t)(mt * 128 + r) * 1024 + nt * 128 + c] = f2bf(fmaxf(v + bias[c], 0.f));
  });
}

// G3: sup2T(256f x 1024k) = Wg2bd(256x1024) @ h1^T   (BT = h1)
__global__ __launch_bounds__(256) void k_g3(const ushort_t* __restrict__ Wg2bd,
                                            const ushort_t* __restrict__ h1,
                                            ushort_t* __restrict__ sup2T) {
  const int nt = blockIdx.x, mt = blockIdx.y, b = blockIdx.z;
  const ushort_t* A  = Wg2bd + (size_t)mt * 128 * 1024;
  const ushort_t* BT = h1 + ((size_t)b << 20) + (size_t)nt * 128 * 1024;
  ushort_t* C = sup2T + (size_t)b * 262144;
  gemm_tile(A, 1024, BT, 1024, 1024, [&](int r, int c, float v) {
    C[(size_t)(mt * 128 + r) * 1024 + nt * 128 + c] = f2bf(v);
  });
}

// G4: g(1024k x 256f) f32 = adj_t @ sup2 + bg2; n-tile 0 -> slice1/f0:128, 1 -> slice4/f128:256
__global__ __launch_bounds__(256) void k_g4(const ushort_t* __restrict__ adjb,
                                            const ushort_t* __restrict__ sup2T,
                                            const float* __restrict__ bg2,
                                            float* __restrict__ g) {
  const int nt = blockIdx.x, mt = blockIdx.y, b = blockIdx.z;
  const ushort_t* A  = adjb + ((size_t)(b * 2 + nt) << 20) + (size_t)mt * 128 * 1024;
  const ushort_t* BT = sup2T + (size_t)b * 262144 + (size_t)nt * 128 * 1024;
  float* C = g + (size_t)b * 262144;
  const float* bias = bg2 + nt * 128;
  gemm_tile(A, 1024, BT, 1024, 1024, [&](int r, int c, float v) {
    C[(size_t)(mt * 128 + r) * 256 + nt * 128 + c] = v + bias[c];
  });
}

// LayerNorm (ddof=1, eps on sd) + residual; writes f32 + bf16 copies. 1 wave/row.
__global__ __launch_bounds__(256) void k_ln(const float* __restrict__ g, const float* __restrict__ gn,
                                            const float* __restrict__ la, const float* __restrict__ lb,
                                            float* __restrict__ glnf, ushort_t* __restrict__ glnb) {
  const int row = blockIdx.x * 4 + (threadIdx.x >> 6);
  const int lane = threadIdx.x & 63;
  const float4 x = ((const float4*)(g + (size_t)row * 256))[lane];
  float s = x.x + x.y + x.z + x.w;
#pragma unroll
  for (int o = 1; o < 64; o <<= 1) s += __shfl_xor(s, o);
  const float mu = s * (1.f / 256.f);
  const float dx = x.x - mu, dy = x.y - mu, dz = x.z - mu, dw = x.w - mu;
  float q = dx * dx + dy * dy + dz * dz + dw * dw;
#pragma unroll
  for (int o = 1; o < 64; o <<= 1) q += __shfl_xor(q, o);
  const float inv = 1.f / (sqrtf(q * (1.f / 255.f)) + 1e-6f);
  const float4 a  = ((const float4*)la)[lane];
  const float4 bb = ((const float4*)lb)[lane];
  const float4 rz = ((const float4*)(gn + (size_t)row * 256))[lane];
  float4 o;
  o.x = a.x * dx * inv + bb.x + rz.x;
  o.y = a.y * dy * inv + bb.y + rz.y;
  o.z = a.z * dz * inv + bb.z + rz.z;
  o.w = a.w * dw * inv + bb.w + rz.w;
  ((float4*)(glnf + (size_t)row * 256))[lane] = o;
  ushort4 h; h.x = f2bf(o.x); h.y = f2bf(o.y); h.z = f2bf(o.z); h.w = f2bf(o.w);
  ((ushort4*)(glnb + (size_t)row * 256))[lane] = h;
}

// F1: t = relu(gln @ Wf1 + bf1)  (M=16384)
__global__ __launch_bounds__(256) void k_f1(const ushort_t* __restrict__ gln,
                                            const ushort_t* __restrict__ Wf1T,
                                            const float* __restrict__ bf1,
                                            ushort_t* __restrict__ tb) {
  const int nt = blockIdx.x, mt = blockIdx.y;
  const ushort_t* A  = gln + (size_t)mt * 128 * 256;
  const ushort_t* BT = Wf1T + (size_t)nt * 128 * 256;
  const float* bias = bf1 + nt * 128;
  gemm_tile(A, 256, BT, 256, 256, [&](int r, int c, float v) {
    tb[(size_t)(mt * 128 + r) * 256 + nt * 128 + c] = f2bf(fmaxf(v + bias[c], 0.f));
  });
}

// F2: out = t @ Wf2 + bf2 + gln
__global__ __launch_bounds__(256) void k_f2(const ushort_t* __restrict__ tb,
                                            const ushort_t* __restrict__ Wf2T,
                                            const float* __restrict__ bf2,
                                            const float* __restrict__ glnf,
                                            float* __restrict__ out) {
  const int nt = blockIdx.x, mt = blockIdx.y;
  const ushort_t* A  = tb + (size_t)mt * 128 * 256;
  const ushort_t* BT = Wf2T + (size_t)nt * 128 * 256;
  const float* bias = bf2 + nt * 128;
  gemm_tile(A, 256, BT, 256, 256, [&](int r, int c, float v) {
    const size_t idx = (size_t)(mt * 128 + r) * 256 + nt * 128 + c;
    out[idx] = v + bias[c] + glnf[idx];
  });
}

extern "C" void kernel_launch(void* const* d_in, const int* in_sizes, int n_in,
                              void* d_out, int out_size, void* d_ws, size_t ws_size,
                              hipStream_t stream) {
  const float* gnodes = (const float*)d_in[0];
  const int*   graph  = (const int*)d_in[1];
  const float* Wg1 = (const float*)d_in[2];
  const float* bg1 = (const float*)d_in[3];
  const float* Wg2 = (const float*)d_in[4];
  const float* bg2 = (const float*)d_in[5];
  const float* Wf1 = (const float*)d_in[6];
  const float* bf1 = (const float*)d_in[7];
  const float* Wf2 = (const float*)d_in[8];
  const float* bf2 = (const float*)d_in[9];
  const float* ln_a = (const float*)d_in[10];
  const float* ln_b = (const float*)d_in[11];

  float* adj_out = (float*)d_out;
  float* out     = (float*)d_out + 83886080;   // (16,5,1024,1024) f32 first

  char* ws = (char*)d_ws;
  ushort_t* adjb  = (ushort_t*)(ws);                      // 67108864 B (16,2,1024,1024) bf16
  ushort_t* Xb    = (ushort_t*)(ws + 67108864);           //  8388608 B
  ushort_t* W1T   = (ushort_t*)(ws + 75497472);           //   524288 B
  ushort_t* Wg2bd = (ushort_t*)(ws + 76021760);           //   524288 B
  ushort_t* Wf1T  = (ushort_t*)(ws + 76546048);           //   131072 B
  ushort_t* Wf2T  = (ushort_t*)(ws + 76677120);           //   131072 B
  ushort_t* sup1T = (ushort_t*)(ws + 76808192);           // 33554432 B
  ushort_t* h1    = (ushort_t*)(ws + 110362624);          // 33554432 B
  ushort_t* sup2T = (ushort_t*)(ws + 143917056);          //  8388608 B  (total 152305664)
  // temporal aliases: sup1T dead after G2 -> g + gln_f32; h1 dead after G3 -> gln_bf16 + t
  float*    gbuf  = (float*)(ws + 76808192);
  float*    glnf  = (float*)(ws + 76808192 + 16777216);
  ushort_t* glnb  = (ushort_t*)(ws + 110362624);
  ushort_t* tbuf  = (ushort_t*)(ws + 110362624 + 8388608);

  k_cast <<<81920, 256, 0, stream>>>(graph, adj_out, adjb);
  k_castX<<<4096, 256, 0, stream>>>(gnodes, Xb);
  k_prepw<<<2560, 256, 0, stream>>>(Wg1, Wg2, Wf1, Wf2, W1T, Wg2bd, Wf1T, Wf2T);

  k_g1<<<dim3(8, 8, 16), 256, 0, stream>>>(W1T, Xb, sup1T);
  k_g2<<<dim3(8, 8, 16), 256, 0, stream>>>(adjb, sup1T, bg1, h1);
  k_g3<<<dim3(8, 2, 16), 256, 0, stream>>>(Wg2bd, h1, sup2T);
  k_g4<<<dim3(2, 8, 16), 256, 0, stream>>>(adjb, sup2T, bg2, gbuf);

  k_ln<<<4096, 256, 0, stream>>>(gbuf, gnodes, ln_a, ln_b, glnf, glnb);

  k_f1<<<dim3(2, 128), 256, 0, stream>>>(glnb, Wf1T, bf1, tbuf);
  k_f2<<<dim3(2, 128), 256, 0, stream>>>(tbuf, Wf2T, bf2, glnf, out);
}

// Round 2
// 720.773 us; speedup vs baseline: 1.0217x; 1.0217x over previous
//
#include <hip/hip_runtime.h>

typedef unsigned short ushort_t;
using short8  = __attribute__((ext_vector_type(8))) short;
using floatx4 = __attribute__((ext_vector_type(4))) float;

__device__ __forceinline__ ushort_t f2bf(float f) {
  unsigned int x = __builtin_bit_cast(unsigned int, f);
  x += 0x7fffu + ((x >> 16) & 1u);           // RNE
  return (ushort_t)(x >> 16);
}

__device__ __forceinline__ void gld16(const ushort_t* g, ushort_t* l) {
  __builtin_amdgcn_global_load_lds(
      (const __attribute__((address_space(1))) void*)(unsigned long long)(uintptr_t)g,
      (__attribute__((address_space(3))) void*)l, 16, 0, 0);
}

// C(128x128) = A(128xK, row-major, lda) @ B, BT = (128 N-rows) x K row-major.
// BK=64: 32 MFMA + 16 ds_read_b128 per barrier pair (halves barrier drains vs BK=32).
// LDS rows are 64 cols = 8 x 16B chunks; stored chunk c holds global chunk c ^ (row&7)
// so global_load_lds dest stays base+lane*16 and ds_read_b128 is 2-way-conflict free.
template <typename F>
__device__ __forceinline__ void gemm_tile(const ushort_t* __restrict__ A, int lda,
                                          const ushort_t* __restrict__ BT, int ldb,
                                          int K, F epi) {
  __shared__ ushort_t As[128 * 64];
  __shared__ ushort_t Bs[128 * 64];

  const int tid  = threadIdx.x;
  const int wave = tid >> 6;
  const int lane = tid & 63;
  const int l15  = lane & 15;
  const int quad = lane >> 4;
  const int wm   = wave >> 1;
  const int wn   = wave & 1;

  // staging: lane -> (row8 = lane>>3, stored chunk = lane&7), global chunk = stored ^ row8
  const int srow8  = lane >> 3;
  const int schunk = lane & 7;
  const int gcol   = ((schunk ^ srow8) * 8);

  const ushort_t* gA = A  + (size_t)(wave * 32 + srow8) * lda + gcol;
  const ushort_t* gB = BT + (size_t)(wave * 32 + srow8) * ldb + gcol;
  ushort_t* lA = As + (wave * 32) * 64;     // wave-uniform LDS bases
  ushort_t* lB = Bs + (wave * 32) * 64;

  floatx4 acc[4][4] = {};

  const int arow0 = (wm * 64 + l15) * 64;
  const int brow0 = (wn * 64 + l15) * 64;
  const int cx    = l15 & 7;

  for (int k0 = 0; k0 < K; k0 += 64) {
#pragma unroll
    for (int ci = 0; ci < 4; ci++) {
      gld16(gA + (size_t)(ci * 8) * lda, lA + ci * 512);
      gld16(gB + (size_t)(ci * 8) * ldb, lB + ci * 512);
    }
    gA += 64; gB += 64;
    __syncthreads();                        // drains vmcnt (global_load_lds) too
#pragma unroll
    for (int ks = 0; ks < 2; ks++) {
      const int cs = ((ks * 4 + quad) ^ cx) * 8;
      short8 af[4], bfr[4];
#pragma unroll
      for (int i = 0; i < 4; i++) af[i]  = *(const short8*)(As + arow0 + i * 1024 + cs);
#pragma unroll
      for (int j = 0; j < 4; j++) bfr[j] = *(const short8*)(Bs + brow0 + j * 1024 + cs);
#pragma unroll
      for (int i = 0; i < 4; i++)
#pragma unroll
        for (int j = 0; j < 4; j++)
          acc[i][j] = __builtin_amdgcn_mfma_f32_16x16x32_bf16(af[i], bfr[j], acc[i][j], 0, 0, 0);
    }
    __syncthreads();                        // reads done before next overwrite
  }

#pragma unroll
  for (int i = 0; i < 4; i++)
#pragma unroll
    for (int j = 0; j < 4; j++)
#pragma unroll
      for (int r = 0; r < 4; r++)
        epi(wm * 64 + i * 16 + quad * 4 + r, wn * 64 + j * 16 + l15, acc[i][j][r]);
}

// ---------------- prep kernels ----------------

// adj slices 1,4 -> bf16 scratch (B,2,K,K)
__global__ __launch_bounds__(256) void k_adjb(const int* __restrict__ graph,
                                              ushort_t* __restrict__ adjb) {
  const size_t i = (size_t)blockIdx.x * 256 + threadIdx.x;   // int4 index
  const size_t e0 = i * 4;
  const unsigned bt = (unsigned)(e0 >> 20);
  const unsigned b = bt >> 1, t = bt & 1;
  const unsigned s = t ? 4u : 1u;
  int4 v = *(const int4*)(graph + (((size_t)(b * 5 + s)) << 20) + (e0 & 0xFFFFFu));
  ushort4 h;
  h.x = f2bf((float)v.x); h.y = f2bf((float)v.y);
  h.z = f2bf((float)v.z); h.w = f2bf((float)v.w);
  *(ushort4*)(adjb + e0) = h;
}

// full adj int32 -> f32 (d_out output 0); pure BW, gates nothing -> launched last
__global__ __launch_bounds__(256) void k_adjf32(const int* __restrict__ graph,
                                                float* __restrict__ adj_out) {
  const size_t i = (size_t)blockIdx.x * 256 + threadIdx.x;
  int4 v = ((const int4*)graph)[i];
  ((float4*)adj_out)[i] = make_float4((float)v.x, (float)v.y, (float)v.z, (float)v.w);
}

// X (B,K,D) f32 -> XT (B,D,K) bf16 via LDS tile transpose
__global__ __launch_bounds__(256) void k_xt(const float* __restrict__ gn,
                                            ushort_t* __restrict__ XT) {
  __shared__ float t[64][68];
  const int b = blockIdx.z, dt = blockIdx.y, kt = blockIdx.x;
  const int r  = threadIdx.x >> 4;
  const int c4 = (threadIdx.x & 15) * 4;
#pragma unroll
  for (int rr = 0; rr < 4; rr++) {
    const int kl = rr * 16 + r;
    float4 v = *(const float4*)(gn + ((size_t)(b * 1024 + kt * 64 + kl)) * 256 + dt * 64 + c4);
    t[kl][c4] = v.x; t[kl][c4 + 1] = v.y; t[kl][c4 + 2] = v.z; t[kl][c4 + 3] = v.w;
  }
  __syncthreads();
#pragma unroll
  for (int rr = 0; rr < 4; rr++) {
    const int dl = rr * 16 + r;
    ushort4 h;
    h.x = f2bf(t[c4][dl]);     h.y = f2bf(t[c4 + 1][dl]);
    h.z = f2bf(t[c4 + 2][dl]); h.w = f2bf(t[c4 + 3][dl]);
    *(ushort4*)(XT + ((size_t)(b * 256 + dt * 64 + dl)) * 1024 + kt * 64 + c4) = h;
  }
}

// W1T[f][d] = Wg1[h][d][ff] (f=h*256+ff); Wg2bd (256x1024) block-diag of Wg2[h]^T;
// Wf1T/Wf2T plain transposes. All bf16.
__global__ __launch_bounds__(256) void k_prepw(const float* __restrict__ Wg1, const float* __restrict__ Wg2,
                                               const float* __restrict__ Wf1, const float* __restrict__ Wf2,
                                               ushort_t* __restrict__ W1T, ushort_t* __restrict__ Wg2bd,
                                               ushort_t* __restrict__ Wf1T, ushort_t* __restrict__ Wf2T) {
  const int i = blockIdx.x * 256 + threadIdx.x;
  if (i < 262144) {
    const int fI = i >> 8, d = i & 255;
    const int h = fI >> 8, ff = fI & 255;
    W1T[i] = f2bf(Wg1[((h << 8) + d) * 256 + ff]);
  } else if (i < 524288) {
    const int j = i - 262144;
    const int r = j >> 10, c = j & 1023;
    const int h = r >> 6, e = r & 63;
    const float v = ((c >> 8) == h) ? Wg2[((h << 8) + (c & 255)) * 64 + e] : 0.f;
    Wg2bd[j] = f2bf(v);
  } else if (i < 589824) {
    const int j = i - 524288;
    const int n = j >> 8, k = j & 255;
    Wf1T[j] = f2bf(Wf1[k * 256 + n]);
  } else if (i < 655360) {
    const int j = i - 589824;
    const int n = j >> 8, k = j & 255;
    Wf2T[j] = f2bf(Wf2[k * 256 + n]);
  }
}

// ---------------- GEMM step kernels ----------------

// AX[b,t] (1024k x 256d) = adj_t @ X    (BT = XT (256d x 1024k))  K=1024
__global__ __launch_bounds__(256) void k_ax(const ushort_t* __restrict__ adjb,
                                            const ushort_t* __restrict__ XT,
                                            ushort_t* __restrict__ AX) {
  const int nt = blockIdx.x, mt = blockIdx.y, bt = blockIdx.z;
  const int b = bt >> 1;
  const ushort_t* A  = adjb + ((size_t)bt << 20) + (size_t)mt * 128 * 1024;
  const ushort_t* BT = XT + ((size_t)b << 18) + (size_t)nt * 128 * 1024;
  ushort_t* C = AX + ((size_t)bt << 18);
  gemm_tile(A, 1024, BT, 1024, 1024, [&](int r, int c, float v) {
    C[(size_t)(mt * 128 + r) * 256 + nt * 128 + c] = f2bf(v);
  });
}

// h1 (1024k x 1024f) = relu(AX[b,t(h)] @ Wg1[h] + bg1)   (BT = W1T)  K=256
__global__ __launch_bounds__(256) void k_h1(const ushort_t* __restrict__ AX,
                                            const ushort_t* __restrict__ W1T,
                                            const float* __restrict__ bg1,
                                            ushort_t* __restrict__ h1) {
  const int nt = blockIdx.x, mt = blockIdx.y, b = blockIdx.z;
  const int t = nt >> 2;                       // head h = nt>>1, t = h>>1 = nt>>2
  const ushort_t* A  = AX + ((size_t)(b * 2 + t) << 18) + (size_t)mt * 128 * 256;
  const ushort_t* BT = W1T + (size_t)nt * 128 * 256;
  ushort_t* C = h1 + ((size_t)b << 20);
  const float* bias = bg1 + nt * 128;
  gemm_tile(A, 256, BT, 256, 256, [&](int r, int c, float v) {
    C[(size_t)(mt * 128 + r) * 1024 + nt * 128 + c] = f2bf(fmaxf(v + bias[c], 0.f));
  });
}

// G3: sup2T(256e x 1024k) = Wg2bd(256x1024) @ h1^T   (BT = h1)  K=1024
__global__ __launch_bounds__(256) void k_g3(const ushort_t* __restrict__ Wg2bd,
                                            const ushort_t* __restrict__ h1,
                                            ushort_t* __restrict__ sup2T) {
  const int nt = blockIdx.x, mt = blockIdx.y, b = blockIdx.z;
  const ushort_t* A  = Wg2bd + (size_t)mt * 128 * 1024;
  const ushort_t* BT = h1 + ((size_t)b << 20) + (size_t)nt * 128 * 1024;
  ushort_t* C = sup2T + (size_t)b * 262144;
  gemm_tile(A, 1024, BT, 1024, 1024, [&](int r, int c, float v) {
    C[(size_t)(mt * 128 + r) * 1024 + nt * 128 + c] = f2bf(v);
  });
}

// G4: g(1024k x 256e) f32 = adj_t @ sup2 + bg2; nt 0 -> slice1/f0:128, 1 -> slice4/f128:256
__global__ __launch_bounds__(256) void k_g4(const ushort_t* __restrict__ adjb,
                                            const ushort_t* __restrict__ sup2T,
                                            const float* __restrict__ bg2,
                                            float* __restrict__ g) {
  const int nt = blockIdx.x, mt = blockIdx.y, b = blockIdx.z;
  const ushort_t* A  = adjb + ((size_t)(b * 2 + nt) << 20) + (size_t)mt * 128 * 1024;
  const ushort_t* BT = sup2T + (size_t)b * 262144 + (size_t)nt * 128 * 1024;
  float* C = g + (size_t)b * 262144;
  const float* bias = bg2 + nt * 128;
  gemm_tile(A, 1024, BT, 1024, 1024, [&](int r, int c, float v) {
    C[(size_t)(mt * 128 + r) * 256 + nt * 128 + c] = v + bias[c];
  });
}

// LayerNorm (ddof=1, eps on sd) + residual; writes f32 + bf16 copies. 1 wave/row.
__global__ __launch_bounds__(256) void k_ln(const float* __restrict__ g, const float* __restrict__ gn,
                                            const float* __restrict__ la, const float* __restrict__ lb,
                                            float* __restrict__ glnf, ushort_t* __restrict__ glnb) {
  const int row = blockIdx.x * 4 + (threadIdx.x >> 6);
  const int lane = threadIdx.x & 63;
  const float4 x = ((const float4*)(g + (size_t)row * 256))[lane];
  float s = x.x + x.y + x.z + x.w;
#pragma unroll
  for (int o = 1; o < 64; o <<= 1) s += __shfl_xor(s, o);
  const float mu = s * (1.f / 256.f);
  const float dx = x.x - mu, dy = x.y - mu, dz = x.z - mu, dw = x.w - mu;
  float q = dx * dx + dy * dy + dz * dz + dw * dw;
#pragma unroll
  for (int o = 1; o < 64; o <<= 1) q += __shfl_xor(q, o);
  const float inv = 1.f / (sqrtf(q * (1.f / 255.f)) + 1e-6f);
  const float4 a  = ((const float4*)la)[lane];
  const float4 bb = ((const float4*)lb)[lane];
  const float4 rz = ((const float4*)(gn + (size_t)row * 256))[lane];
  float4 o;
  o.x = a.x * dx * inv + bb.x + rz.x;
  o.y = a.y * dy * inv + bb.y + rz.y;
  o.z = a.z * dz * inv + bb.z + rz.z;
  o.w = a.w * dw * inv + bb.w + rz.w;
  ((float4*)(glnf + (size_t)row * 256))[lane] = o;
  ushort4 h; h.x = f2bf(o.x); h.y = f2bf(o.y); h.z = f2bf(o.z); h.w = f2bf(o.w);
  ((ushort4*)(glnb + (size_t)row * 256))[lane] = h;
}

// F1: t = relu(gln @ Wf1 + bf1)  (M=16384, K=256)
__global__ __launch_bounds__(256) void k_f1(const ushort_t* __restrict__ gln,
                                            const ushort_t* __restrict__ Wf1T,
                                            const float* __restrict__ bf1,
                                            ushort_t* __restrict__ tb) {
  const int nt = blockIdx.x, mt = blockIdx.y;
  const ushort_t* A  = gln + (size_t)mt * 128 * 256;
  const ushort_t* BT = Wf1T + (size_t)nt * 128 * 256;
  const float* bias = bf1 + nt * 128;
  gemm_tile(A, 256, BT, 256, 256, [&](int r, int c, float v) {
    tb[(size_t)(mt * 128 + r) * 256 + nt * 128 + c] = f2bf(fmaxf(v + bias[c], 0.f));
  });
}

// F2: out = t @ Wf2 + bf2 + gln
__global__ __launch_bounds__(256) void k_f2(const ushort_t* __restrict__ tb,
                                            const ushort_t* __restrict__ Wf2T,
                                            const float* __restrict__ bf2,
                                            const float* __restrict__ glnf,
                                            float* __restrict__ out) {
  const int nt = blockIdx.x, mt = blockIdx.y;
  const ushort_t* A  = tb + (size_t)mt * 128 * 256;
  const ushort_t* BT = Wf2T + (size_t)nt * 128 * 256;
  const float* bias = bf2 + nt * 128;
  gemm_tile(A, 256, BT, 256, 256, [&](int r, int c, float v) {
    const size_t idx = (size_t)(mt * 128 + r) * 256 + nt * 128 + c;
    out[idx] = v + bias[c] + glnf[idx];
  });
}

extern "C" void kernel_launch(void* const* d_in, const int* in_sizes, int n_in,
                              void* d_out, int out_size, void* d_ws, size_t ws_size,
                              hipStream_t stream) {
  const float* gnodes = (const float*)d_in[0];
  const int*   graph  = (const int*)d_in[1];
  const float* Wg1 = (const float*)d_in[2];
  const float* bg1 = (const float*)d_in[3];
  const float* Wg2 = (const float*)d_in[4];
  const float* bg2 = (const float*)d_in[5];
  const float* Wf1 = (const float*)d_in[6];
  const float* bf1 = (const float*)d_in[7];
  const float* Wf2 = (const float*)d_in[8];
  const float* bf2 = (const float*)d_in[9];
  const float* ln_a = (const float*)d_in[10];
  const float* ln_b = (const float*)d_in[11];

  float* adj_out = (float*)d_out;
  float* out     = (float*)d_out + 83886080;   // (16,5,1024,1024) f32 first

  char* ws = (char*)d_ws;
  ushort_t* adjb  = (ushort_t*)(ws);                       //  67108864 B (16,2,1024,1024)
  ushort_t* XT    = (ushort_t*)(ws + 67108864);            //   8388608 B (16,256,1024)
  ushort_t* W1T   = (ushort_t*)(ws + 75497472);            //    524288 B
  ushort_t* Wg2bd = (ushort_t*)(ws + 76021760);            //    524288 B
  ushort_t* Wf1T  = (ushort_t*)(ws + 76546048);            //    131072 B
  ushort_t* Wf2T  = (ushort_t*)(ws + 76677120);            //    131072 B
  ushort_t* AX    = (ushort_t*)(ws + 76808192);            //  16777216 B (16,2,1024,256)
  ushort_t* h1    = (ushort_t*)(ws + 93585408);            //  33554432 B
  ushort_t* sup2T = (ushort_t*)(ws + 127139840);           //   8388608 B
  float*    gbuf  = (float*)(ws + 135528448);              //  16777216 B
  float*    glnf  = (float*)(ws + 152305664);              //  16777216 B
  ushort_t* glnb  = (ushort_t*)(ws + 169082880);           //   8388608 B
  ushort_t* tbuf  = (ushort_t*)(ws + 177471488);           //   8388608 B  (tot 185 MB)

  k_adjb <<<32768, 256, 0, stream>>>(graph, adjb);
  k_xt   <<<dim3(16, 4, 16), 256, 0, stream>>>(gnodes, XT);
  k_prepw<<<2560, 256, 0, stream>>>(Wg1, Wg2, Wf1, Wf2, W1T, Wg2bd, Wf1T, Wf2T);

  k_ax<<<dim3(2, 8, 32), 256, 0, stream>>>(adjb, XT, AX);
  k_h1<<<dim3(8, 8, 16), 256, 0, stream>>>(AX, W1T, bg1, h1);
  k_g3<<<dim3(8, 2, 16), 256, 0, stream>>>(Wg2bd, h1, sup2T);
  k_g4<<<dim3(2, 8, 16), 256, 0, stream>>>(adjb, sup2T, bg2, gbuf);

  k_ln<<<4096, 256, 0, stream>>>(gbuf, gnodes, ln_a, ln_b, glnf, glnb);

  k_f1<<<dim3(2, 128), 256, 0, stream>>>(glnb, Wf1T, bf1, tbuf);
  k_f2<<<dim3(2, 128), 256, 0, stream>>>(tbuf, Wf2T, bf2, glnf, out);

  k_adjf32<<<81920, 256, 0, stream>>>(graph, adj_out);
}

// Round 3
// 712.649 us; speedup vs baseline: 1.0334x; 1.0114x over previous
//
#include <hip/hip_runtime.h>

typedef unsigned short ushort_t;
using short8  = __attribute__((ext_vector_type(8))) short;
using floatx4 = __attribute__((ext_vector_type(4))) float;

__device__ __forceinline__ ushort_t f2bf(float f) {
  unsigned int x = __builtin_bit_cast(unsigned int, f);
  x += 0x7fffu + ((x >> 16) & 1u);           // RNE
  return (ushort_t)(x >> 16);
}

__device__ __forceinline__ void gld16(const ushort_t* g, ushort_t* l) {
  __builtin_amdgcn_global_load_lds(
      (const __attribute__((address_space(1))) void*)(unsigned long long)(uintptr_t)g,
      (__attribute__((address_space(3))) void*)l, 16, 0, 0);
}

// ---------- 128x128 tile, 256 threads (4 waves 2x2), BK=64 ----------
// LDS rows are 64 cols = 8 x 16B chunks; stored chunk c holds global chunk c ^ (row&7).
template <typename F>
__device__ __forceinline__ void gemm_tile(const ushort_t* __restrict__ A, int lda,
                                          const ushort_t* __restrict__ BT, int ldb,
                                          int K, F epi) {
  __shared__ ushort_t As[128 * 64];
  __shared__ ushort_t Bs[128 * 64];

  const int tid  = threadIdx.x;
  const int wave = tid >> 6;
  const int lane = tid & 63;
  const int l15  = lane & 15;
  const int quad = lane >> 4;
  const int wm   = wave >> 1;
  const int wn   = wave & 1;

  const int srow8  = lane >> 3;
  const int schunk = lane & 7;
  const int gcol   = ((schunk ^ srow8) * 8);

  const ushort_t* gA = A  + (size_t)(wave * 32 + srow8) * lda + gcol;
  const ushort_t* gB = BT + (size_t)(wave * 32 + srow8) * ldb + gcol;
  ushort_t* lA = As + (wave * 32) * 64;
  ushort_t* lB = Bs + (wave * 32) * 64;

  floatx4 acc[4][4] = {};
  const int arow0 = (wm * 64 + l15) * 64;
  const int brow0 = (wn * 64 + l15) * 64;
  const int cx    = l15 & 7;

  for (int k0 = 0; k0 < K; k0 += 64) {
#pragma unroll
    for (int ci = 0; ci < 4; ci++) {
      gld16(gA + (size_t)(ci * 8) * lda, lA + ci * 512);
      gld16(gB + (size_t)(ci * 8) * ldb, lB + ci * 512);
    }
    gA += 64; gB += 64;
    __syncthreads();
#pragma unroll
    for (int ks = 0; ks < 2; ks++) {
      const int cs = ((ks * 4 + quad) ^ cx) * 8;
      short8 af[4], bfr[4];
#pragma unroll
      for (int i = 0; i < 4; i++) af[i]  = *(const short8*)(As + arow0 + i * 1024 + cs);
#pragma unroll
      for (int j = 0; j < 4; j++) bfr[j] = *(const short8*)(Bs + brow0 + j * 1024 + cs);
#pragma unroll
      for (int i = 0; i < 4; i++)
#pragma unroll
        for (int j = 0; j < 4; j++)
          acc[i][j] = __builtin_amdgcn_mfma_f32_16x16x32_bf16(af[i], bfr[j], acc[i][j], 0, 0, 0);
    }
    __syncthreads();
  }

#pragma unroll
  for (int i = 0; i < 4; i++)
#pragma unroll
    for (int j = 0; j < 4; j++)
#pragma unroll
      for (int r = 0; r < 4; r++)
        epi(wm * 64 + i * 16 + quad * 4 + r, wn * 64 + j * 16 + l15, acc[i][j][r]);
}

// ---------- 128x256 tile, 512 threads (8 waves 2x4), BK=64 ----------
template <typename F>
__device__ __forceinline__ void gemm_tile_w(const ushort_t* __restrict__ A, int lda,
                                            const ushort_t* __restrict__ BT, int ldb,
                                            int K, F epi) {
  __shared__ ushort_t As[128 * 64];   // 16 KB
  __shared__ ushort_t Bs[256 * 64];   // 32 KB

  const int tid  = threadIdx.x;
  const int wave = tid >> 6;          // 0..7
  const int lane = tid & 63;
  const int l15  = lane & 15;
  const int quad = lane >> 4;
  const int wm   = wave >> 2;         // 0..1
  const int wn   = wave & 3;          // 0..3

  const int srow8  = lane >> 3;
  const int schunk = lane & 7;
  const int gcol   = ((schunk ^ srow8) * 8);

  const ushort_t* gA = A  + (size_t)(wave * 16 + srow8) * lda + gcol;
  const ushort_t* gB = BT + (size_t)(wave * 32 + srow8) * ldb + gcol;
  ushort_t* lA = As + (wave * 16) * 64;
  ushort_t* lB = Bs + (wave * 32) * 64;

  floatx4 acc[4][4] = {};
  const int arow0 = (wm * 64 + l15) * 64;
  const int brow0 = (wn * 64 + l15) * 64;
  const int cx    = l15 & 7;

  for (int k0 = 0; k0 < K; k0 += 64) {
#pragma unroll
    for (int ci = 0; ci < 2; ci++)
      gld16(gA + (size_t)(ci * 8) * lda, lA + ci * 512);
#pragma unroll
    for (int ci = 0; ci < 4; ci++)
      gld16(gB + (size_t)(ci * 8) * ldb, lB + ci * 512);
    gA += 64; gB += 64;
    __syncthreads();
#pragma unroll
    for (int ks = 0; ks < 2; ks++) {
      const int cs = ((ks * 4 + quad) ^ cx) * 8;
      short8 af[4], bfr[4];
#pragma unroll
      for (int i = 0; i < 4; i++) af[i]  = *(const short8*)(As + arow0 + i * 1024 + cs);
#pragma unroll
      for (int j = 0; j < 4; j++) bfr[j] = *(const short8*)(Bs + brow0 + j * 1024 + cs);
#pragma unroll
      for (int i = 0; i < 4; i++)
#pragma unroll
        for (int j = 0; j < 4; j++)
          acc[i][j] = __builtin_amdgcn_mfma_f32_16x16x32_bf16(af[i], bfr[j], acc[i][j], 0, 0, 0);
    }
    __syncthreads();
  }

#pragma unroll
  for (int i = 0; i < 4; i++)
#pragma unroll
    for (int j = 0; j < 4; j++)
#pragma unroll
      for (int r = 0; r < 4; r++)
        epi(wm * 64 + i * 16 + quad * 4 + r, wn * 64 + j * 16 + l15, acc[i][j][r]);
}

// ---------------- prep kernels ----------------

// fused adj cast: int32 (B,5,K,K) -> f32 to d_out; slices 1,4 also -> bf16 scratch.
__global__ __launch_bounds__(256) void k_cast(const int* __restrict__ graph,
                                              float* __restrict__ adj_out,
                                              ushort_t* __restrict__ adjb) {
  const size_t i = (size_t)blockIdx.x * 256 + threadIdx.x;   // int4 index
  int4 v = ((const int4*)graph)[i];
  float4 f = make_float4((float)v.x, (float)v.y, (float)v.z, (float)v.w);
  ((float4*)adj_out)[i] = f;
  const size_t e0 = i * 4;
  const unsigned sb = (unsigned)(e0 >> 20);
  const unsigned s = sb % 5u, b = sb / 5u;
  if (s == 1u || s == 4u) {
    const unsigned tt = (s == 4u) ? 1u : 0u;
    ushort4 h;
    h.x = f2bf(f.x); h.y = f2bf(f.y); h.z = f2bf(f.z); h.w = f2bf(f.w);
    *(ushort4*)(adjb + (((size_t)(b * 2 + tt)) << 20) + (e0 & 0xFFFFFu)) = h;
  }
}

// X (B,K,D) f32 -> XT (B,D,K) bf16 via LDS tile transpose
__global__ __launch_bounds__(256) void k_xt(const float* __restrict__ gn,
                                            ushort_t* __restrict__ XT) {
  __shared__ float t[64][68];
  const int b = blockIdx.z, dt = blockIdx.y, kt = blockIdx.x;
  const int r  = threadIdx.x >> 4;
  const int c4 = (threadIdx.x & 15) * 4;
#pragma unroll
  for (int rr = 0; rr < 4; rr++) {
    const int kl = rr * 16 + r;
    float4 v = *(const float4*)(gn + ((size_t)(b * 1024 + kt * 64 + kl)) * 256 + dt * 64 + c4);
    t[kl][c4] = v.x; t[kl][c4 + 1] = v.y; t[kl][c4 + 2] = v.z; t[kl][c4 + 3] = v.w;
  }
  __syncthreads();
#pragma unroll
  for (int rr = 0; rr < 4; rr++) {
    const int dl = rr * 16 + r;
    ushort4 h;
    h.x = f2bf(t[c4][dl]);     h.y = f2bf(t[c4 + 1][dl]);
    h.z = f2bf(t[c4 + 2][dl]); h.w = f2bf(t[c4 + 3][dl]);
    *(ushort4*)(XT + ((size_t)(b * 256 + dt * 64 + dl)) * 1024 + kt * 64 + c4) = h;
  }
}

// W1T[f][d] = Wg1[h][d][ff]; W2pT[t] (128 e' x 512 k) per-pair block-diag of Wg2^T;
// Wf1T/Wf2T plain transposes. All bf16.
__global__ __launch_bounds__(256) void k_prepw(const float* __restrict__ Wg1, const float* __restrict__ Wg2,
                                               const float* __restrict__ Wf1, const float* __restrict__ Wf2,
                                               ushort_t* __restrict__ W1T, ushort_t* __restrict__ W2pT,
                                               ushort_t* __restrict__ Wf1T, ushort_t* __restrict__ Wf2T) {
  const int i = blockIdx.x * 256 + threadIdx.x;
  if (i < 262144) {
    const int fI = i >> 8, d = i & 255;
    const int h = fI >> 8, ff = fI & 255;
    W1T[i] = f2bf(Wg1[((h << 8) + d) * 256 + ff]);
  } else if (i < 393216) {
    const int j = i - 262144;                 // t(1) | e'(7) | k(9)
    const int t = j >> 16, rem = j & 65535;
    const int ep = rem >> 9, k = rem & 511;
    const int hh = ep >> 6;                   // head within pair
    const float v = ((k >> 8) == hh)
        ? Wg2[(((t * 2 + hh) << 8) + (k & 255)) * 64 + (ep & 63)] : 0.f;
    W2pT[j] = f2bf(v);
  } else if (i < 458752) {
    const int j = i - 393216;
    const int n = j >> 8, k = j & 255;
    Wf1T[j] = f2bf(Wf1[k * 256 + n]);
  } else if (i < 524288) {
    const int j = i - 458752;
    const int n = j >> 8, k = j & 255;
    Wf2T[j] = f2bf(Wf2[k * 256 + n]);
  }
}

// ---------------- GEMM step kernels ----------------

// AX[b,t] (1024k x 256d) = adj_t @ X   (BT = XT[b], 256 rows x 1024)  K=1024, wide tile
__global__ __launch_bounds__(512) void k_ax(const ushort_t* __restrict__ adjb,
                                            const ushort_t* __restrict__ XT,
                                            ushort_t* __restrict__ AX) {
  const int mt = blockIdx.x, bt = blockIdx.y;
  const int b = bt >> 1;
  const ushort_t* A  = adjb + ((size_t)bt << 20) + (size_t)mt * 128 * 1024;
  const ushort_t* BT = XT + ((size_t)b << 18);
  ushort_t* C = AX + ((size_t)bt << 18);
  gemm_tile_w(A, 1024, BT, 1024, 1024, [&](int r, int c, float v) {
    C[(size_t)(mt * 128 + r) * 256 + c] = f2bf(v);
  });
}

// h1 (1024k x 1024f) = relu(AX[b,t(h)] @ Wg1[h] + bg1); nt covers one head (256 f). K=256, wide
__global__ __launch_bounds__(512) void k_h1(const ushort_t* __restrict__ AX,
                                            const ushort_t* __restrict__ W1T,
                                            const float* __restrict__ bg1,
                                            ushort_t* __restrict__ h1) {
  const int nt = blockIdx.x, mt = blockIdx.y, b = blockIdx.z;
  const int t = nt >> 1;                       // head h = nt
  const ushort_t* A  = AX + ((size_t)(b * 2 + t) << 18) + (size_t)mt * 128 * 256;
  const ushort_t* BT = W1T + ((size_t)nt << 16);
  ushort_t* C = h1 + ((size_t)b << 20);
  const float* bias = bg1 + nt * 256;
  gemm_tile_w(A, 256, BT, 256, 256, [&](int r, int c, float v) {
    C[(size_t)(mt * 128 + r) * 1024 + nt * 256 + c] = f2bf(fmaxf(v + bias[c], 0.f));
  });
}

// G3: sup2T[b,t](128e' x 1024k') = W2pT[t](128x512) @ h1[b][:, t*512:+512]^T   K=512
__global__ __launch_bounds__(256) void k_g3(const ushort_t* __restrict__ W2pT,
                                            const ushort_t* __restrict__ h1,
                                            ushort_t* __restrict__ sup2T) {
  const int nt = blockIdx.x, bt = blockIdx.y;
  const int b = bt >> 1, t = bt & 1;
  const ushort_t* A  = W2pT + (size_t)t * 65536;
  const ushort_t* BT = h1 + ((size_t)b << 20) + (size_t)nt * 131072 + t * 512;
  ushort_t* C = sup2T + (size_t)bt * 131072;
  gemm_tile(A, 512, BT, 1024, 512, [&](int r, int c, float v) {
    C[(size_t)r * 1024 + nt * 128 + c] = f2bf(v);
  });
}

// G4: g(1024k x 256f) f32 = adj_t @ sup2 + bg2; nt=t -> cols [t*128, t*128+128)
__global__ __launch_bounds__(256) void k_g4(const ushort_t* __restrict__ adjb,
                                            const ushort_t* __restrict__ sup2T,
                                            const float* __restrict__ bg2,
                                            float* __restrict__ g) {
  const int nt = blockIdx.x, mt = blockIdx.y, b = blockIdx.z;
  const ushort_t* A  = adjb + ((size_t)(b * 2 + nt) << 20) + (size_t)mt * 128 * 1024;
  const ushort_t* BT = sup2T + (size_t)(b * 2 + nt) * 131072;
  float* C = g + (size_t)b * 262144;
  const float* bias = bg2 + nt * 128;
  gemm_tile(A, 1024, BT, 1024, 1024, [&](int r, int c, float v) {
    C[(size_t)(mt * 128 + r) * 256 + nt * 128 + c] = v + bias[c];
  });
}

// LayerNorm (ddof=1, eps on sd) + residual; writes f32 + bf16 copies. 1 wave/row.
__global__ __launch_bounds__(256) void k_ln(const float* __restrict__ g, const float* __restrict__ gn,
                                            const float* __restrict__ la, const float* __restrict__ lb,
                                            float* __restrict__ glnf, ushort_t* __restrict__ glnb) {
  const int row = blockIdx.x * 4 + (threadIdx.x >> 6);
  const int lane = threadIdx.x & 63;
  const float4 x = ((const float4*)(g + (size_t)row * 256))[lane];
  float s = x.x + x.y + x.z + x.w;
#pragma unroll
  for (int o = 1; o < 64; o <<= 1) s += __shfl_xor(s, o);
  const float mu = s * (1.f / 256.f);
  const float dx = x.x - mu, dy = x.y - mu, dz = x.z - mu, dw = x.w - mu;
  float q = dx * dx + dy * dy + dz * dz + dw * dw;
#pragma unroll
  for (int o = 1; o < 64; o <<= 1) q += __shfl_xor(q, o);
  const float inv = 1.f / (sqrtf(q * (1.f / 255.f)) + 1e-6f);
  const float4 a  = ((const float4*)la)[lane];
  const float4 bb = ((const float4*)lb)[lane];
  const float4 rz = ((const float4*)(gn + (size_t)row * 256))[lane];
  float4 o;
  o.x = a.x * dx * inv + bb.x + rz.x;
  o.y = a.y * dy * inv + bb.y + rz.y;
  o.z = a.z * dz * inv + bb.z + rz.z;
  o.w = a.w * dw * inv + bb.w + rz.w;
  ((float4*)(glnf + (size_t)row * 256))[lane] = o;
  ushort4 h; h.x = f2bf(o.x); h.y = f2bf(o.y); h.z = f2bf(o.z); h.w = f2bf(o.w);
  ((ushort4*)(glnb + (size_t)row * 256))[lane] = h;
}

// F1: t = relu(gln @ Wf1 + bf1)  (M=16384, K=256)
__global__ __launch_bounds__(256) void k_f1(const ushort_t* __restrict__ gln,
                                            const ushort_t* __restrict__ Wf1T,
                                            const float* __restrict__ bf1,
                                            ushort_t* __restrict__ tb) {
  const int nt = blockIdx.x, mt = blockIdx.y;
  const ushort_t* A  = gln + (size_t)mt * 128 * 256;
  const ushort_t* BT = Wf1T + (size_t)nt * 128 * 256;
  const float* bias = bf1 + nt * 128;
  gemm_tile(A, 256, BT, 256, 256, [&](int r, int c, float v) {
    tb[(size_t)(mt * 128 + r) * 256 + nt * 128 + c] = f2bf(fmaxf(v + bias[c], 0.f));
  });
}

// F2: out = t @ Wf2 + bf2 + gln
__global__ __launch_bounds__(256) void k_f2(const ushort_t* __restrict__ tb,
                                            const ushort_t* __restrict__ Wf2T,
                                            const float* __restrict__ bf2,
                                            const float* __restrict__ glnf,
                                            float* __restrict__ out) {
  const int nt = blockIdx.x, mt = blockIdx.y;
  const ushort_t* A  = tb + (size_t)mt * 128 * 256;
  const ushort_t* BT = Wf2T + (size_t)nt * 128 * 256;
  const float* bias = bf2 + nt * 128;
  gemm_tile(A, 256, BT, 256, 256, [&](int r, int c, float v) {
    const size_t idx = (size_t)(mt * 128 + r) * 256 + nt * 128 + c;
    out[idx] = v + bias[c] + glnf[idx];
  });
}

extern "C" void kernel_launch(void* const* d_in, const int* in_sizes, int n_in,
                              void* d_out, int out_size, void* d_ws, size_t ws_size,
                              hipStream_t stream) {
  const float* gnodes = (const float*)d_in[0];
  const int*   graph  = (const int*)d_in[1];
  const float* Wg1 = (const float*)d_in[2];
  const float* bg1 = (const float*)d_in[3];
  const float* Wg2 = (const float*)d_in[4];
  const float* bg2 = (const float*)d_in[5];
  const float* Wf1 = (const float*)d_in[6];
  const float* bf1 = (const float*)d_in[7];
  const float* Wf2 = (const float*)d_in[8];
  const float* bf2 = (const float*)d_in[9];
  const float* ln_a = (const float*)d_in[10];
  const float* ln_b = (const float*)d_in[11];

  float* adj_out = (float*)d_out;
  float* out     = (float*)d_out + 83886080;   // (16,5,1024,1024) f32 first

  char* ws = (char*)d_ws;
  ushort_t* adjb  = (ushort_t*)(ws);                       //  67108864 B (16,2,1024,1024)
  ushort_t* XT    = (ushort_t*)(ws + 67108864);            //   8388608 B (16,256,1024)
  ushort_t* W1T   = (ushort_t*)(ws + 75497472);            //    524288 B
  ushort_t* W2pT  = (ushort_t*)(ws + 76021760);            //    262144 B (2,128,512)
  ushort_t* Wf1T  = (ushort_t*)(ws + 76283904);            //    131072 B
  ushort_t* Wf2T  = (ushort_t*)(ws + 76414976);            //    131072 B
  ushort_t* AX    = (ushort_t*)(ws + 76546048);            //  16777216 B (16,2,1024,256)
  ushort_t* h1    = (ushort_t*)(ws + 93323264);            //  33554432 B
  ushort_t* sup2T = (ushort_t*)(ws + 126877696);           //   8388608 B (16,2,128,1024)
  float*    gbuf  = (float*)(ws + 135266304);              //  16777216 B
  float*    glnf  = (float*)(ws + 152043520);              //  16777216 B
  ushort_t* glnb  = (ushort_t*)(ws + 168820736);           //   8388608 B
  ushort_t* tbuf  = (ushort_t*)(ws + 177209344);           //   8388608 B  (tot 186 MB)

  k_xt   <<<dim3(16, 4, 16), 256, 0, stream>>>(gnodes, XT);
  k_prepw<<<2048, 256, 0, stream>>>(Wg1, Wg2, Wf1, Wf2, W1T, W2pT, Wf1T, Wf2T);
  k_cast <<<81920, 256, 0, stream>>>(graph, adj_out, adjb);

  k_ax<<<dim3(8, 32), 512, 0, stream>>>(adjb, XT, AX);
  k_h1<<<dim3(4, 8, 16), 512, 0, stream>>>(AX, W1T, bg1, h1);
  k_g3<<<dim3(8, 32), 256, 0, stream>>>(W2pT, h1, sup2T);
  k_g4<<<dim3(2, 8, 16), 256, 0, stream>>>(adjb, sup2T, bg2, gbuf);

  k_ln<<<4096, 256, 0, stream>>>(gbuf, gnodes, ln_a, ln_b, glnf, glnb);

  k_f1<<<dim3(2, 128), 256, 0, stream>>>(glnb, Wf1T, bf1, tbuf);
  k_f2<<<dim3(2, 128), 256, 0, stream>>>(tbuf, Wf2T, bf2, glnf, out);
}

// Round 4
// 710.519 us; speedup vs baseline: 1.0365x; 1.0030x over previous
//
#include <hip/hip_runtime.h>

typedef unsigned short ushort_t;
using short8  = __attribute__((ext_vector_type(8))) short;
using floatx4 = __attribute__((ext_vector_type(4))) float;

__device__ __forceinline__ ushort_t f2bf(float f) {
  unsigned int x = __builtin_bit_cast(unsigned int, f);
  x += 0x7fffu + ((x >> 16) & 1u);           // RNE
  return (ushort_t)(x >> 16);
}

__device__ __forceinline__ float bf2f(ushort_t h) {
  return __builtin_bit_cast(float, (unsigned int)h << 16);
}

__device__ __forceinline__ void gld16(const ushort_t* g, ushort_t* l) {
  __builtin_amdgcn_global_load_lds(
      (const __attribute__((address_space(1))) void*)(unsigned long long)(uintptr_t)g,
      (__attribute__((address_space(3))) void*)l, 16, 0, 0);
}

// ---------- 128x128 tile, 256 threads (4 waves 2x2), BK=64 ----------
// LDS rows are 64 cols = 8 x 16B chunks; stored chunk c holds global chunk c ^ (row&7).
template <typename F>
__device__ __forceinline__ void gemm_tile(const ushort_t* __restrict__ A, int lda,
                                          const ushort_t* __restrict__ BT, int ldb,
                                          int K, F epi) {
  __shared__ ushort_t As[128 * 64];
  __shared__ ushort_t Bs[128 * 64];

  const int tid  = threadIdx.x;
  const int wave = tid >> 6;
  const int lane = tid & 63;
  const int l15  = lane & 15;
  const int quad = lane >> 4;
  const int wm   = wave >> 1;
  const int wn   = wave & 1;

  const int srow8  = lane >> 3;
  const int schunk = lane & 7;
  const int gcol   = ((schunk ^ srow8) * 8);

  const ushort_t* gA = A  + (size_t)(wave * 32 + srow8) * lda + gcol;
  const ushort_t* gB = BT + (size_t)(wave * 32 + srow8) * ldb + gcol;
  ushort_t* lA = As + (wave * 32) * 64;
  ushort_t* lB = Bs + (wave * 32) * 64;

  floatx4 acc[4][4] = {};
  const int arow0 = (wm * 64 + l15) * 64;
  const int brow0 = (wn * 64 + l15) * 64;
  const int cx    = l15 & 7;

  for (int k0 = 0; k0 < K; k0 += 64) {
#pragma unroll
    for (int ci = 0; ci < 4; ci++) {
      gld16(gA + (size_t)(ci * 8) * lda, lA + ci * 512);
      gld16(gB + (size_t)(ci * 8) * ldb, lB + ci * 512);
    }
    gA += 64; gB += 64;
    __syncthreads();
#pragma unroll
    for (int ks = 0; ks < 2; ks++) {
      const int cs = ((ks * 4 + quad) ^ cx) * 8;
      short8 af[4], bfr[4];
#pragma unroll
      for (int i = 0; i < 4; i++) af[i]  = *(const short8*)(As + arow0 + i * 1024 + cs);
#pragma unroll
      for (int j = 0; j < 4; j++) bfr[j] = *(const short8*)(Bs + brow0 + j * 1024 + cs);
#pragma unroll
      for (int i = 0; i < 4; i++)
#pragma unroll
        for (int j = 0; j < 4; j++)
          acc[i][j] = __builtin_amdgcn_mfma_f32_16x16x32_bf16(af[i], bfr[j], acc[i][j], 0, 0, 0);
    }
    __syncthreads();
  }

#pragma unroll
  for (int i = 0; i < 4; i++)
#pragma unroll
    for (int j = 0; j < 4; j++)
#pragma unroll
      for (int r = 0; r < 4; r++)
        epi(wm * 64 + i * 16 + quad * 4 + r, wn * 64 + j * 16 + l15, acc[i][j][r]);
}

// ---------------- prep kernels ----------------

// fused adj cast: int32 (B,5,K,K) -> f32 to d_out; slices 1,4 also -> bf16 scratch.
__global__ __launch_bounds__(256) void k_cast(const int* __restrict__ graph,
                                              float* __restrict__ adj_out,
                                              ushort_t* __restrict__ adjb) {
  const size_t i = (size_t)blockIdx.x * 256 + threadIdx.x;   // int4 index
  int4 v = ((const int4*)graph)[i];
  float4 f = make_float4((float)v.x, (float)v.y, (float)v.z, (float)v.w);
  ((float4*)adj_out)[i] = f;
  const size_t e0 = i * 4;
  const unsigned sb = (unsigned)(e0 >> 20);
  const unsigned s = sb % 5u, b = sb / 5u;
  if (s == 1u || s == 4u) {
    const unsigned tt = (s == 4u) ? 1u : 0u;
    ushort4 h;
    h.x = f2bf(f.x); h.y = f2bf(f.y); h.z = f2bf(f.z); h.w = f2bf(f.w);
    *(ushort4*)(adjb + (((size_t)(b * 2 + tt)) << 20) + (e0 & 0xFFFFFu)) = h;
  }
}

// X (B,K,D) f32 -> XT (B,D,K) bf16 via LDS tile transpose
__global__ __launch_bounds__(256) void k_xt(const float* __restrict__ gn,
                                            ushort_t* __restrict__ XT) {
  __shared__ float t[64][68];
  const int b = blockIdx.z, dt = blockIdx.y, kt = blockIdx.x;
  const int r  = threadIdx.x >> 4;
  const int c4 = (threadIdx.x & 15) * 4;
#pragma unroll
  for (int rr = 0; rr < 4; rr++) {
    const int kl = rr * 16 + r;
    float4 v = *(const float4*)(gn + ((size_t)(b * 1024 + kt * 64 + kl)) * 256 + dt * 64 + c4);
    t[kl][c4] = v.x; t[kl][c4 + 1] = v.y; t[kl][c4 + 2] = v.z; t[kl][c4 + 3] = v.w;
  }
  __syncthreads();
#pragma unroll
  for (int rr = 0; rr < 4; rr++) {
    const int dl = rr * 16 + r;
    ushort4 h;
    h.x = f2bf(t[c4][dl]);     h.y = f2bf(t[c4 + 1][dl]);
    h.z = f2bf(t[c4 + 2][dl]); h.w = f2bf(t[c4 + 3][dl]);
    *(ushort4*)(XT + ((size_t)(b * 256 + dt * 64 + dl)) * 1024 + kt * 64 + c4) = h;
  }
}

// W1T[f][d] = Wg1[h][d][ff]; W2pT[t] (128 e' x 512 k) per-pair block-diag of Wg2^T;
// Wf1T/Wf2T plain transposes. All bf16.
__global__ __launch_bounds__(256) void k_prepw(const float* __restrict__ Wg1, const float* __restrict__ Wg2,
                                               const float* __restrict__ Wf1, const float* __restrict__ Wf2,
                                               ushort_t* __restrict__ W1T, ushort_t* __restrict__ W2pT,
                                               ushort_t* __restrict__ Wf1T, ushort_t* __restrict__ Wf2T) {
  const int i = blockIdx.x * 256 + threadIdx.x;
  if (i < 262144) {
    const int fI = i >> 8, d = i & 255;
    const int h = fI >> 8, ff = fI & 255;
    W1T[i] = f2bf(Wg1[((h << 8) + d) * 256 + ff]);
  } else if (i < 393216) {
    const int j = i - 262144;                 // t(1) | e'(7) | k(9)
    const int t = j >> 16, rem = j & 65535;
    const int ep = rem >> 9, k = rem & 511;
    const int hh = ep >> 6;                   // head within pair
    const float v = ((k >> 8) == hh)
        ? Wg2[(((t * 2 + hh) << 8) + (k & 255)) * 64 + (ep & 63)] : 0.f;
    W2pT[j] = f2bf(v);
  } else if (i < 458752) {
    const int j = i - 393216;
    const int n = j >> 8, k = j & 255;
    Wf1T[j] = f2bf(Wf1[k * 256 + n]);
  } else if (i < 524288) {
    const int j = i - 458752;
    const int n = j >> 8, k = j & 255;
    Wf2T[j] = f2bf(Wf2[k * 256 + n]);
  }
}

// ---------------- GEMM step kernels ----------------

// AX[b,t] (1024k x 256d) = adj_t @ X   (BT = XT[b])  K=1024
__global__ __launch_bounds__(256) void k_ax(const ushort_t* __restrict__ adjb,
                                            const ushort_t* __restrict__ XT,
                                            ushort_t* __restrict__ AX) {
  const int nt = blockIdx.x, mt = blockIdx.y, bt = blockIdx.z;
  const int b = bt >> 1;
  const ushort_t* A  = adjb + ((size_t)bt << 20) + (size_t)mt * 128 * 1024;
  const ushort_t* BT = XT + ((size_t)b << 18) + (size_t)nt * 128 * 1024;
  ushort_t* C = AX + ((size_t)bt << 18);
  gemm_tile(A, 1024, BT, 1024, 1024, [&](int r, int c, float v) {
    C[(size_t)(mt * 128 + r) * 256 + nt * 128 + c] = f2bf(v);
  });
}

// h1 (1024k x 1024f) = relu(AX[b,t(h)] @ Wg1[h] + bg1)   (BT = W1T)  K=256
__global__ __launch_bounds__(256) void k_h1(const ushort_t* __restrict__ AX,
                                            const ushort_t* __restrict__ W1T,
                                            const float* __restrict__ bg1,
                                            ushort_t* __restrict__ h1) {
  const int nt = blockIdx.x, mt = blockIdx.y, b = blockIdx.z;
  const int t = nt >> 2;                       // head h = nt>>1
  const ushort_t* A  = AX + ((size_t)(b * 2 + t) << 18) + (size_t)mt * 128 * 256;
  const ushort_t* BT = W1T + (size_t)nt * 128 * 256;
  ushort_t* C = h1 + ((size_t)b << 20);
  const float* bias = bg1 + nt * 128;
  gemm_tile(A, 256, BT, 256, 256, [&](int r, int c, float v) {
    C[(size_t)(mt * 128 + r) * 1024 + nt * 128 + c] = f2bf(fmaxf(v + bias[c], 0.f));
  });
}

// G3: sup2T[b,t](128e' x 1024k') = W2pT[t](128x512) @ h1[b][:, t*512:+512]^T   K=512
__global__ __launch_bounds__(256) void k_g3(const ushort_t* __restrict__ W2pT,
                                            const ushort_t* __restrict__ h1,
                                            ushort_t* __restrict__ sup2T) {
  const int nt = blockIdx.x, bt = blockIdx.y;
  const int b = bt >> 1, t = bt & 1;
  const ushort_t* A  = W2pT + (size_t)t * 65536;
  const ushort_t* BT = h1 + ((size_t)b << 20) + (size_t)nt * 131072 + t * 512;
  ushort_t* C = sup2T + (size_t)bt * 131072;
  gemm_tile(A, 512, BT, 1024, 512, [&](int r, int c, float v) {
    C[(size_t)r * 1024 + nt * 128 + c] = f2bf(v);
  });
}

// Fused G4 + bias + LayerNorm(ddof=1, eps on sd) + residual -> glnb (bf16).
// Block: 64 rows x 256 cols, 4 waves side by side (wave wn -> cols wn*64..+64,
// t = wn>>1 selects adj slice / sup2 half). K=1024.
__global__ __launch_bounds__(256) void k_g4ln(const ushort_t* __restrict__ adjb,
                                              const ushort_t* __restrict__ sup2T,
                                              const float* __restrict__ bg2,
                                              const float* __restrict__ gn,
                                              const float* __restrict__ la,
                                              const float* __restrict__ lb,
                                              ushort_t* __restrict__ glnb) {
  __shared__ ushort_t As[128 * 64];            // [t*64 + row][64]
  __shared__ ushort_t Bs[256 * 64];            // [t*128 + e'][64]
  __shared__ float sred[4][64], qred[4][64];

  const int mt = blockIdx.x, b = blockIdx.y;
  const int tid = threadIdx.x, wave = tid >> 6, lane = tid & 63;
  const int l15 = lane & 15, quad = lane >> 4;
  const int wn = wave;                         // 0..3 (col group)
  const int tsel = wn >> 1;

  const int srow8 = lane >> 3, schunk = lane & 7;
  const int gcol = (schunk ^ srow8) * 8;

  // A staging: waves 0,1 -> slice t=0 rows {0..31},{32..63}; waves 2,3 -> slice t=1
  const ushort_t* adjt = adjb + ((size_t)(b * 2 + tsel) << 20) + (size_t)(mt * 64) * 1024;
  const ushort_t* gA = adjt + (size_t)((wave & 1) * 32 + srow8) * 1024 + gcol;
  // B staging: waves 0,1 -> sup2T[b,0] rows {0..63},{64..127}; waves 2,3 -> sup2T[b,1]
  const ushort_t* supt = sup2T + (size_t)(b * 2 + tsel) * 131072;
  const ushort_t* gB = supt + (size_t)((wave & 1) * 64 + srow8) * 1024 + gcol;
  ushort_t* lA = As + (wave * 32) * 64;
  ushort_t* lB = Bs + (wave * 64) * 64;

  floatx4 acc[4][4] = {};
  const int arow0 = (tsel * 64 + l15) * 64;    // A rows for this wave's slice
  const int brow0 = (wn * 64 + l15) * 64;      // B rows = global col
  const int cx = l15 & 7;

  for (int k0 = 0; k0 < 1024; k0 += 64) {
#pragma unroll
    for (int ci = 0; ci < 4; ci++)
      gld16(gA + (size_t)(ci * 8) * 1024, lA + ci * 512);
#pragma unroll
    for (int ci = 0; ci < 8; ci++)
      gld16(gB + (size_t)(ci * 8) * 1024, lB + ci * 512);
    gA += 64; gB += 64;
    __syncthreads();
#pragma unroll
    for (int ks = 0; ks < 2; ks++) {
      const int cs = ((ks * 4 + quad) ^ cx) * 8;
      short8 af[4], bfr[4];
#pragma unroll
      for (int i = 0; i < 4; i++) af[i]  = *(const short8*)(As + arow0 + i * 1024 + cs);
#pragma unroll
      for (int j = 0; j < 4; j++) bfr[j] = *(const short8*)(Bs + brow0 + j * 1024 + cs);
#pragma unroll
      for (int i = 0; i < 4; i++)
#pragma unroll
        for (int j = 0; j < 4; j++)
          acc[i][j] = __builtin_amdgcn_mfma_f32_16x16x32_bf16(af[i], bfr[j], acc[i][j], 0, 0, 0);
    }
    __syncthreads();
  }

  // bias (LN input = adj@sup2 + bg2)
  float laj[4], lbj[4];
#pragma unroll
  for (int j = 0; j < 4; j++) {
    const int colg = wn * 64 + j * 16 + l15;
    const float bj = bg2[colg];
    laj[j] = la[colg]; lbj[j] = lb[colg];
#pragma unroll
    for (int i = 0; i < 4; i++)
#pragma unroll
      for (int r = 0; r < 4; r++) acc[i][j][r] += bj;
  }

  // per-row partial sums over this wave's 64 cols
  float sv[4][4], qv[4][4];
#pragma unroll
  for (int i = 0; i < 4; i++)
#pragma unroll
    for (int r = 0; r < 4; r++) {
      float s = 0.f, q = 0.f;
#pragma unroll
      for (int j = 0; j < 4; j++) { const float v = acc[i][j][r]; s += v; q += v * v; }
#pragma unroll
      for (int m = 1; m < 16; m <<= 1) { s += __shfl_xor(s, m); q += __shfl_xor(q, m); }
      sv[i][r] = s; qv[i][r] = q;
    }
  if (l15 == 0) {
#pragma unroll
    for (int i = 0; i < 4; i++)
#pragma unroll
      for (int r = 0; r < 4; r++) {
        const int row = i * 16 + quad * 4 + r;
        sred[wn][row] = sv[i][r]; qred[wn][row] = qv[i][r];
      }
  }
  __syncthreads();

  const size_t rowbase = (size_t)(b * 1024 + mt * 64);
#pragma unroll
  for (int i = 0; i < 4; i++)
#pragma unroll
    for (int r = 0; r < 4; r++) {
      const int row = i * 16 + quad * 4 + r;
      const float S = sred[0][row] + sred[1][row] + sred[2][row] + sred[3][row];
      const float Q = qred[0][row] + qred[1][row] + qred[2][row] + qred[3][row];
      const float mu = S * (1.f / 256.f);
      const float var = fmaxf((Q - S * mu) * (1.f / 255.f), 0.f);
      const float inv = 1.f / (sqrtf(var) + 1e-6f);
      const float* gnr = gn + (rowbase + row) * 256;
      ushort_t* outr = glnb + (rowbase + row) * 256;
#pragma unroll
      for (int j = 0; j < 4; j++) {
        const int colg = wn * 64 + j * 16 + l15;
        const float o = laj[j] * (acc[i][j][r] - mu) * inv + lbj[j] + gnr[colg];
        outr[colg] = f2bf(o);
      }
    }
}

// F1: t = relu(gln @ Wf1 + bf1)  (M=16384, K=256)
__global__ __launch_bounds__(256) void k_f1(const ushort_t* __restrict__ gln,
                                            const ushort_t* __restrict__ Wf1T,
                                            const float* __restrict__ bf1,
                                            ushort_t* __restrict__ tb) {
  const int nt = blockIdx.x, mt = blockIdx.y;
  const ushort_t* A  = gln + (size_t)mt * 128 * 256;
  const ushort_t* BT = Wf1T + (size_t)nt * 128 * 256;
  const float* bias = bf1 + nt * 128;
  gemm_tile(A, 256, BT, 256, 256, [&](int r, int c, float v) {
    tb[(size_t)(mt * 128 + r) * 256 + nt * 128 + c] = f2bf(fmaxf(v + bias[c], 0.f));
  });
}

// F2: out = t @ Wf2 + bf2 + gln (residual from bf16 LN copy)
__global__ __launch_bounds__(256) void k_f2(const ushort_t* __restrict__ tb,
                                            const ushort_t* __restrict__ Wf2T,
                                            const float* __restrict__ bf2,
                                            const ushort_t* __restrict__ glnb,
                                            float* __restrict__ out) {
  const int nt = blockIdx.x, mt = blockIdx.y;
  const ushort_t* A  = tb + (size_t)mt * 128 * 256;
  const ushort_t* BT = Wf2T + (size_t)nt * 128 * 256;
  const float* bias = bf2 + nt * 128;
  gemm_tile(A, 256, BT, 256, 256, [&](int r, int c, float v) {
    const size_t idx = (size_t)(mt * 128 + r) * 256 + nt * 128 + c;
    out[idx] = v + bias[c] + bf2f(glnb[idx]);
  });
}

extern "C" void kernel_launch(void* const* d_in, const int* in_sizes, int n_in,
                              void* d_out, int out_size, void* d_ws, size_t ws_size,
                              hipStream_t stream) {
  const float* gnodes = (const float*)d_in[0];
  const int*   graph  = (const int*)d_in[1];
  const float* Wg1 = (const float*)d_in[2];
  const float* bg1 = (const float*)d_in[3];
  const float* Wg2 = (const float*)d_in[4];
  const float* bg2 = (const float*)d_in[5];
  const float* Wf1 = (const float*)d_in[6];
  const float* bf1 = (const float*)d_in[7];
  const float* Wf2 = (const float*)d_in[8];
  const float* bf2 = (const float*)d_in[9];
  const float* ln_a = (const float*)d_in[10];
  const float* ln_b = (const float*)d_in[11];

  float* adj_out = (float*)d_out;
  float* out     = (float*)d_out + 83886080;   // (16,5,1024,1024) f32 first

  char* ws = (char*)d_ws;
  ushort_t* adjb  = (ushort_t*)(ws);                       //  67108864 B (16,2,1024,1024)
  ushort_t* XT    = (ushort_t*)(ws + 67108864);            //   8388608 B (16,256,1024)
  ushort_t* W1T   = (ushort_t*)(ws + 75497472);            //    524288 B
  ushort_t* W2pT  = (ushort_t*)(ws + 76021760);            //    262144 B (2,128,512)
  ushort_t* Wf1T  = (ushort_t*)(ws + 76283904);            //    131072 B
  ushort_t* Wf2T  = (ushort_t*)(ws + 76414976);            //    131072 B
  ushort_t* AX    = (ushort_t*)(ws + 76546048);            //  16777216 B (16,2,1024,256)
  ushort_t* h1    = (ushort_t*)(ws + 93323264);            //  33554432 B
  ushort_t* sup2T = (ushort_t*)(ws + 126877696);           //   8388608 B (16,2,128,1024)
  ushort_t* glnb  = (ushort_t*)(ws + 135266304);           //   8388608 B
  ushort_t* tbuf  = (ushort_t*)(ws + 143654912);           //   8388608 B  (tot 152 MB)

  k_xt   <<<dim3(16, 4, 16), 256, 0, stream>>>(gnodes, XT);
  k_prepw<<<2048, 256, 0, stream>>>(Wg1, Wg2, Wf1, Wf2, W1T, W2pT, Wf1T, Wf2T);
  k_cast <<<81920, 256, 0, stream>>>(graph, adj_out, adjb);

  k_ax<<<dim3(2, 8, 32), 256, 0, stream>>>(adjb, XT, AX);
  k_h1<<<dim3(8, 8, 16), 256, 0, stream>>>(AX, W1T, bg1, h1);
  k_g3<<<dim3(8, 32), 256, 0, stream>>>(W2pT, h1, sup2T);
  k_g4ln<<<dim3(16, 16), 256, 0, stream>>>(adjb, sup2T, bg2, gnodes, ln_a, ln_b, glnb);

  k_f1<<<dim3(2, 128), 256, 0, stream>>>(glnb, Wf1T, bf1, tbuf);
  k_f2<<<dim3(2, 128), 256, 0, stream>>>(tbuf, Wf2T, bf2, glnb, out);
}

// Round 5
// 693.442 us; speedup vs baseline: 1.0620x; 1.0246x over previous
//
#include <hip/hip_runtime.h>

typedef unsigned short ushort_t;
using short8  = __attribute__((ext_vector_type(8))) short;
using floatx4 = __attribute__((ext_vector_type(4))) float;

__device__ __forceinline__ ushort_t f2bf(float f) {
  unsigned int x = __builtin_bit_cast(unsigned int, f);
  x += 0x7fffu + ((x >> 16) & 1u);           // RNE
  return (ushort_t)(x >> 16);
}

__device__ __forceinline__ float bf2f(ushort_t h) {
  return __builtin_bit_cast(float, (unsigned int)h << 16);
}

__device__ __forceinline__ void gld16(const ushort_t* g, ushort_t* l) {
  __builtin_amdgcn_global_load_lds(
      (const __attribute__((address_space(1))) void*)(unsigned long long)(uintptr_t)g,
      (__attribute__((address_space(3))) void*)l, 16, 0, 0);
}

// ---------- 128x128 tile, 256 threads (4 waves 2x2), BK=64 ----------
// LDS rows are 64 cols = 8 x 16B chunks; stored chunk c holds global chunk c ^ (row&7).
template <typename F>
__device__ __forceinline__ void gemm_tile(const ushort_t* __restrict__ A, int lda,
                                          const ushort_t* __restrict__ BT, int ldb,
                                          int K, F epi) {
  __shared__ ushort_t As[128 * 64];
  __shared__ ushort_t Bs[128 * 64];

  const int tid  = threadIdx.x;
  const int wave = tid >> 6;
  const int lane = tid & 63;
  const int l15  = lane & 15;
  const int quad = lane >> 4;
  const int wm   = wave >> 1;
  const int wn   = wave & 1;

  const int srow8  = lane >> 3;
  const int schunk = lane & 7;
  const int gcol   = ((schunk ^ srow8) * 8);

  const ushort_t* gA = A  + (size_t)(wave * 32 + srow8) * lda + gcol;
  const ushort_t* gB = BT + (size_t)(wave * 32 + srow8) * ldb + gcol;
  ushort_t* lA = As + (wave * 32) * 64;
  ushort_t* lB = Bs + (wave * 32) * 64;

  floatx4 acc[4][4] = {};
  const int arow0 = (wm * 64 + l15) * 64;
  const int brow0 = (wn * 64 + l15) * 64;
  const int cx    = l15 & 7;

  for (int k0 = 0; k0 < K; k0 += 64) {
#pragma unroll
    for (int ci = 0; ci < 4; ci++) {
      gld16(gA + (size_t)(ci * 8) * lda, lA + ci * 512);
      gld16(gB + (size_t)(ci * 8) * ldb, lB + ci * 512);
    }
    gA += 64; gB += 64;
    __syncthreads();
#pragma unroll
    for (int ks = 0; ks < 2; ks++) {
      const int cs = ((ks * 4 + quad) ^ cx) * 8;
      short8 af[4], bfr[4];
#pragma unroll
      for (int i = 0; i < 4; i++) af[i]  = *(const short8*)(As + arow0 + i * 1024 + cs);
#pragma unroll
      for (int j = 0; j < 4; j++) bfr[j] = *(const short8*)(Bs + brow0 + j * 1024 + cs);
#pragma unroll
      for (int i = 0; i < 4; i++)
#pragma unroll
        for (int j = 0; j < 4; j++)
          acc[i][j] = __builtin_amdgcn_mfma_f32_16x16x32_bf16(af[i], bfr[j], acc[i][j], 0, 0, 0);
    }
    __syncthreads();
  }

#pragma unroll
  for (int i = 0; i < 4; i++)
#pragma unroll
    for (int j = 0; j < 4; j++)
#pragma unroll
      for (int r = 0; r < 4; r++)
        epi(wm * 64 + i * 16 + quad * 4 + r, wn * 64 + j * 16 + l15, acc[i][j][r]);
}

// ---------- 64x128 tile, 256 threads (4 waves 2x2, wave=32x64), BK=64 ----------
// Light tile for short-K / tail GEMMs: 24 KB LDS, acc 2x4 -> low VGPR, 2+ blocks/CU.
template <typename F>
__device__ __forceinline__ void gemm_tile64(const ushort_t* __restrict__ A, int lda,
                                            const ushort_t* __restrict__ BT, int ldb,
                                            int K, F epi) {
  __shared__ ushort_t As[64 * 64];    // 8 KB
  __shared__ ushort_t Bs[128 * 64];   // 16 KB

  const int tid  = threadIdx.x;
  const int wave = tid >> 6;
  const int lane = tid & 63;
  const int l15  = lane & 15;
  const int quad = lane >> 4;
  const int wm   = wave >> 1;
  const int wn   = wave & 1;

  const int srow8  = lane >> 3;
  const int schunk = lane & 7;
  const int gcol   = ((schunk ^ srow8) * 8);

  const ushort_t* gA = A  + (size_t)(wave * 16 + srow8) * lda + gcol;
  const ushort_t* gB = BT + (size_t)(wave * 32 + srow8) * ldb + gcol;
  ushort_t* lA = As + (wave * 16) * 64;
  ushort_t* lB = Bs + (wave * 32) * 64;

  floatx4 acc[2][4] = {};
  const int arow0 = (wm * 32 + l15) * 64;
  const int brow0 = (wn * 64 + l15) * 64;
  const int cx    = l15 & 7;

  for (int k0 = 0; k0 < K; k0 += 64) {
#pragma unroll
    for (int ci = 0; ci < 2; ci++)
      gld16(gA + (size_t)(ci * 8) * lda, lA + ci * 512);
#pragma unroll
    for (int ci = 0; ci < 4; ci++)
      gld16(gB + (size_t)(ci * 8) * ldb, lB + ci * 512);
    gA += 64; gB += 64;
    __syncthreads();
#pragma unroll
    for (int ks = 0; ks < 2; ks++) {
      const int cs = ((ks * 4 + quad) ^ cx) * 8;
      short8 af[2], bfr[4];
#pragma unroll
      for (int i = 0; i < 2; i++) af[i]  = *(const short8*)(As + arow0 + i * 1024 + cs);
#pragma unroll
      for (int j = 0; j < 4; j++) bfr[j] = *(const short8*)(Bs + brow0 + j * 1024 + cs);
#pragma unroll
      for (int i = 0; i < 2; i++)
#pragma unroll
        for (int j = 0; j < 4; j++)
          acc[i][j] = __builtin_amdgcn_mfma_f32_16x16x32_bf16(af[i], bfr[j], acc[i][j], 0, 0, 0);
    }
    __syncthreads();
  }

#pragma unroll
  for (int i = 0; i < 2; i++)
#pragma unroll
    for (int j = 0; j < 4; j++)
#pragma unroll
      for (int r = 0; r < 4; r++)
        epi(wm * 32 + i * 16 + quad * 4 + r, wn * 64 + j * 16 + l15, acc[i][j][r]);
}

// ---------------- prep kernels ----------------

// fused adj cast: int32 (B,5,K,K) -> f32 to d_out; slices 1,4 also -> bf16 scratch.
__global__ __launch_bounds__(256) void k_cast(const int* __restrict__ graph,
                                              float* __restrict__ adj_out,
                                              ushort_t* __restrict__ adjb) {
  const size_t i = (size_t)blockIdx.x * 256 + threadIdx.x;   // int4 index
  int4 v = ((const int4*)graph)[i];
  float4 f = make_float4((float)v.x, (float)v.y, (float)v.z, (float)v.w);
  ((float4*)adj_out)[i] = f;
  const size_t e0 = i * 4;
  const unsigned sb = (unsigned)(e0 >> 20);
  const unsigned s = sb % 5u, b = sb / 5u;
  if (s == 1u || s == 4u) {
    const unsigned tt = (s == 4u) ? 1u : 0u;
    ushort4 h;
    h.x = f2bf(f.x); h.y = f2bf(f.y); h.z = f2bf(f.z); h.w = f2bf(f.w);
    *(ushort4*)(adjb + (((size_t)(b * 2 + tt)) << 20) + (e0 & 0xFFFFFu)) = h;
  }
}

// X (B,K,D) f32 -> XT (B,D,K) bf16 via LDS tile transpose
__global__ __launch_bounds__(256) void k_xt(const float* __restrict__ gn,
                                            ushort_t* __restrict__ XT) {
  __shared__ float t[64][68];
  const int b = blockIdx.z, dt = blockIdx.y, kt = blockIdx.x;
  const int r  = threadIdx.x >> 4;
  const int c4 = (threadIdx.x & 15) * 4;
#pragma unroll
  for (int rr = 0; rr < 4; rr++) {
    const int kl = rr * 16 + r;
    float4 v = *(const float4*)(gn + ((size_t)(b * 1024 + kt * 64 + kl)) * 256 + dt * 64 + c4);
    t[kl][c4] = v.x; t[kl][c4 + 1] = v.y; t[kl][c4 + 2] = v.z; t[kl][c4 + 3] = v.w;
  }
  __syncthreads();
#pragma unroll
  for (int rr = 0; rr < 4; rr++) {
    const int dl = rr * 16 + r;
    ushort4 h;
    h.x = f2bf(t[c4][dl]);     h.y = f2bf(t[c4 + 1][dl]);
    h.z = f2bf(t[c4 + 2][dl]); h.w = f2bf(t[c4 + 3][dl]);
    *(ushort4*)(XT + ((size_t)(b * 256 + dt * 64 + dl)) * 1024 + kt * 64 + c4) = h;
  }
}

// W1T[f][d] = Wg1[h][d][ff]; W2pT[t] (128 e' x 512 k) per-pair block-diag of Wg2^T;
// Wf1T/Wf2T plain transposes. All bf16.
__global__ __launch_bounds__(256) void k_prepw(const float* __restrict__ Wg1, const float* __restrict__ Wg2,
                                               const float* __restrict__ Wf1, const float* __restrict__ Wf2,
                                               ushort_t* __restrict__ W1T, ushort_t* __restrict__ W2pT,
                                               ushort_t* __restrict__ Wf1T, ushort_t* __restrict__ Wf2T) {
  const int i = blockIdx.x * 256 + threadIdx.x;
  if (i < 262144) {
    const int fI = i >> 8, d = i & 255;
    const int h = fI >> 8, ff = fI & 255;
    W1T[i] = f2bf(Wg1[((h << 8) + d) * 256 + ff]);
  } else if (i < 393216) {
    const int j = i - 262144;                 // t(1) | e'(7) | k(9)
    const int t = j >> 16, rem = j & 65535;
    const int ep = rem >> 9, k = rem & 511;
    const int hh = ep >> 6;                   // head within pair
    const float v = ((k >> 8) == hh)
        ? Wg2[(((t * 2 + hh) << 8) + (k & 255)) * 64 + (ep & 63)] : 0.f;
    W2pT[j] = f2bf(v);
  } else if (i < 458752) {
    const int j = i - 393216;
    const int n = j >> 8, k = j & 255;
    Wf1T[j] = f2bf(Wf1[k * 256 + n]);
  } else if (i < 524288) {
    const int j = i - 458752;
    const int n = j >> 8, k = j & 255;
    Wf2T[j] = f2bf(Wf2[k * 256 + n]);
  }
}

// ---------------- GEMM step kernels ----------------

// AX[b,t] (1024k x 256d) = adj_t @ X   (BT = XT[b])  K=1024
__global__ __launch_bounds__(256) void k_ax(const ushort_t* __restrict__ adjb,
                                            const ushort_t* __restrict__ XT,
                                            ushort_t* __restrict__ AX) {
  const int nt = blockIdx.x, mt = blockIdx.y, bt = blockIdx.z;
  const int b = bt >> 1;
  const ushort_t* A  = adjb + ((size_t)bt << 20) + (size_t)mt * 128 * 1024;
  const ushort_t* BT = XT + ((size_t)b << 18) + (size_t)nt * 128 * 1024;
  ushort_t* C = AX + ((size_t)bt << 18);
  gemm_tile(A, 1024, BT, 1024, 1024, [&](int r, int c, float v) {
    C[(size_t)(mt * 128 + r) * 256 + nt * 128 + c] = f2bf(v);
  });
}

// h1 (1024k x 1024f) = relu(AX[b,t(h)] @ Wg1[h] + bg1)   (BT = W1T)  K=256
__global__ __launch_bounds__(256) void k_h1(const ushort_t* __restrict__ AX,
                                            const ushort_t* __restrict__ W1T,
                                            const float* __restrict__ bg1,
                                            ushort_t* __restrict__ h1) {
  const int nt = blockIdx.x, mt = blockIdx.y, b = blockIdx.z;
  const int t = nt >> 2;                       // head h = nt>>1
  const ushort_t* A  = AX + ((size_t)(b * 2 + t) << 18) + (size_t)mt * 128 * 256;
  const ushort_t* BT = W1T + (size_t)nt * 128 * 256;
  ushort_t* C = h1 + ((size_t)b << 20);
  const float* bias = bg1 + nt * 128;
  gemm_tile(A, 256, BT, 256, 256, [&](int r, int c, float v) {
    C[(size_t)(mt * 128 + r) * 1024 + nt * 128 + c] = f2bf(fmaxf(v + bias[c], 0.f));
  });
}

// G3: sup2T[b,t](128e' x 1024k') = W2pT[t](128x512) @ h1[b][:, t*512:+512]^T   K=512
// 64x128 tiles: grid (2 m-half, 8 nt, 32 bt) = 512 blocks
__global__ __launch_bounds__(256) void k_g3(const ushort_t* __restrict__ W2pT,
                                            const ushort_t* __restrict__ h1,
                                            ushort_t* __restrict__ sup2T) {
  const int mx = blockIdx.x, nt = blockIdx.y, bt = blockIdx.z;
  const int b = bt >> 1, t = bt & 1;
  const ushort_t* A  = W2pT + (size_t)t * 65536 + (size_t)mx * 64 * 512;
  const ushort_t* BT = h1 + ((size_t)b << 20) + (size_t)nt * 131072 + t * 512;
  ushort_t* C = sup2T + (size_t)bt * 131072;
  gemm_tile64(A, 512, BT, 1024, 512, [&](int r, int c, float v) {
    C[(size_t)(mx * 64 + r) * 1024 + nt * 128 + c] = f2bf(v);
  });
}

// Fused G4 + bias + LayerNorm(ddof=1, eps on sd) + residual -> glnb (bf16).
// Block: 32 rows x 256 cols, 4 waves side by side (wave wn -> cols wn*64..+64,
// t = wn>>1 selects adj slice / sup2 half). K=1024. Grid (32 mt, 16 b) = 512.
__global__ __launch_bounds__(256) void k_g4ln(const ushort_t* __restrict__ adjb,
                                              const ushort_t* __restrict__ sup2T,
                                              const float* __restrict__ bg2,
                                              const float* __restrict__ gn,
                                              const float* __restrict__ la,
                                              const float* __restrict__ lb,
                                              ushort_t* __restrict__ glnb) {
  __shared__ ushort_t As[64 * 64];             // rows 0..31 slice0, 32..63 slice1 (8 KB)
  __shared__ ushort_t Bs[256 * 64];            // feature rows 0..255 (32 KB)
  __shared__ float sred[4][32], qred[4][32];

  const int mt = blockIdx.x, b = blockIdx.y;
  const int tid = threadIdx.x, wave = tid >> 6, lane = tid & 63;
  const int l15 = lane & 15, quad = lane >> 4;
  const int wn = wave;                         // 0..3 (col group)
  const int tsel = wn >> 1;

  const int srow8 = lane >> 3, schunk = lane & 7;
  const int gcol = (schunk ^ srow8) * 8;

  // A staging: wave w stages As rows w*16..+16: slice w>>1, local rows mt*32 + (w&1)*16
  const ushort_t* gA = adjb + ((size_t)(b * 2 + (wave >> 1)) << 20)
                     + (size_t)(mt * 32 + (wave & 1) * 16 + srow8) * 1024 + gcol;
  // B staging: wave w stages Bs rows w*64..+64: t = w>>1, e' rows (w&1)*64..+64
  const ushort_t* gB = sup2T + (size_t)(b * 2 + (wave >> 1)) * 131072
                     + (size_t)((wave & 1) * 64 + srow8) * 1024 + gcol;
  ushort_t* lA = As + (wave * 16) * 64;
  ushort_t* lB = Bs + (wave * 64) * 64;

  floatx4 acc[2][4] = {};
  const int arow0 = (tsel * 32 + l15) * 64;    // A rows for this wave's slice
  const int brow0 = (wn * 64 + l15) * 64;      // B rows = global feature col
  const int cx = l15 & 7;

  for (int k0 = 0; k0 < 1024; k0 += 64) {
#pragma unroll
    for (int ci = 0; ci < 2; ci++)
      gld16(gA + (size_t)(ci * 8) * 1024, lA + ci * 512);
#pragma unroll
    for (int ci = 0; ci < 8; ci++)
      gld16(gB + (size_t)(ci * 8) * 1024, lB + ci * 512);
    gA += 64; gB += 64;
    __syncthreads();
#pragma unroll
    for (int ks = 0; ks < 2; ks++) {
      const int cs = ((ks * 4 + quad) ^ cx) * 8;
      short8 af[2], bfr[4];
#pragma unroll
      for (int i = 0; i < 2; i++) af[i]  = *(const short8*)(As + arow0 + i * 1024 + cs);
#pragma unroll
      for (int j = 0; j < 4; j++) bfr[j] = *(const short8*)(Bs + brow0 + j * 1024 + cs);
#pragma unroll
      for (int i = 0; i < 2; i++)
#pragma unroll
        for (int j = 0; j < 4; j++)
          acc[i][j] = __builtin_amdgcn_mfma_f32_16x16x32_bf16(af[i], bfr[j], acc[i][j], 0, 0, 0);
    }
    __syncthreads();
  }

  // bias (LN input = adj@sup2 + bg2)
  float laj[4], lbj[4];
#pragma unroll
  for (int j = 0; j < 4; j++) {
    const int colg = wn * 64 + j * 16 + l15;
    const float bj = bg2[colg];
    laj[j] = la[colg]; lbj[j] = lb[colg];
#pragma unroll
    for (int i = 0; i < 2; i++)
#pragma unroll
      for (int r = 0; r < 4; r++) acc[i][j][r] += bj;
  }

  // per-row partial sums over this wave's 64 cols
#pragma unroll
  for (int i = 0; i < 2; i++)
#pragma unroll
    for (int r = 0; r < 4; r++) {
      float s = 0.f, q = 0.f;
#pragma unroll
      for (int j = 0; j < 4; j++) { const float v = acc[i][j][r]; s += v; q += v * v; }
#pragma unroll
      for (int m = 1; m < 16; m <<= 1) { s += __shfl_xor(s, m); q += __shfl_xor(q, m); }
      if (l15 == 0) {
        const int row = i * 16 + quad * 4 + r;
        sred[wn][row] = s; qred[wn][row] = q;
      }
    }
  __syncthreads();

  const size_t rowbase = (size_t)(b * 1024 + mt * 32);
#pragma unroll
  for (int i = 0; i < 2; i++)
#pragma unroll
    for (int r = 0; r < 4; r++) {
      const int row = i * 16 + quad * 4 + r;
      const float S = sred[0][row] + sred[1][row] + sred[2][row] + sred[3][row];
      const float Q = qred[0][row] + qred[1][row] + qred[2][row] + qred[3][row];
      const float mu = S * (1.f / 256.f);
      const float var = fmaxf((Q - S * mu) * (1.f / 255.f), 0.f);
      const float inv = 1.f / (sqrtf(var) + 1e-6f);
      const float* gnr = gn + (rowbase + row) * 256;
      ushort_t* outr = glnb + (rowbase + row) * 256;
#pragma unroll
      for (int j = 0; j < 4; j++) {
        const int colg = wn * 64 + j * 16 + l15;
        const float o = laj[j] * (acc[i][j][r] - mu) * inv + lbj[j] + gnr[colg];
        outr[colg] = f2bf(o);
      }
    }
}

// F1: t = relu(gln @ Wf1 + bf1)  (M=16384, K=256), 64-row tiles -> 512 blocks
__global__ __launch_bounds__(256) void k_f1(const ushort_t* __restrict__ gln,
                                            const ushort_t* __restrict__ Wf1T,
                                            const float* __restrict__ bf1,
                                            ushort_t* __restrict__ tb) {
  const int nt = blockIdx.x, mt = blockIdx.y;
  const ushort_t* A  = gln + (size_t)mt * 64 * 256;
  const ushort_t* BT = Wf1T + (size_t)nt * 128 * 256;
  const float* bias = bf1 + nt * 128;
  gemm_tile64(A, 256, BT, 256, 256, [&](int r, int c, float v) {
    tb[(size_t)(mt * 64 + r) * 256 + nt * 128 + c] = f2bf(fmaxf(v + bias[c], 0.f));
  });
}

// F2: out = t @ Wf2 + bf2 + gln (residual from bf16 LN copy), 64-row tiles -> 512 blocks
__global__ __launch_bounds__(256) void k_f2(const ushort_t* __restrict__ tb,
                                            const ushort_t* __restrict__ Wf2T,
                                            const float* __restrict__ bf2,
                                            const ushort_t* __restrict__ glnb,
                                            float* __restrict__ out) {
  const int nt = blockIdx.x, mt = blockIdx.y;
  const ushort_t* A  = tb + (size_t)mt * 64 * 256;
  const ushort_t* BT = Wf2T + (size_t)nt * 128 * 256;
  const float* bias = bf2 + nt * 128;
  gemm_tile64(A, 256, BT, 256, 256, [&](int r, int c, float v) {
    const size_t idx = (size_t)(mt * 64 + r) * 256 + nt * 128 + c;
    out[idx] = v + bias[c] + bf2f(glnb[idx]);
  });
}

extern "C" void kernel_launch(void* const* d_in, const int* in_sizes, int n_in,
                              void* d_out, int out_size, void* d_ws, size_t ws_size,
                              hipStream_t stream) {
  const float* gnodes = (const float*)d_in[0];
  const int*   graph  = (const int*)d_in[1];
  const float* Wg1 = (const float*)d_in[2];
  const float* bg1 = (const float*)d_in[3];
  const float* Wg2 = (const float*)d_in[4];
  const float* bg2 = (const float*)d_in[5];
  const float* Wf1 = (const float*)d_in[6];
  const float* bf1 = (const float*)d_in[7];
  const float* Wf2 = (const float*)d_in[8];
  const float* bf2 = (const float*)d_in[9];
  const float* ln_a = (const float*)d_in[10];
  const float* ln_b = (const float*)d_in[11];

  float* adj_out = (float*)d_out;
  float* out     = (float*)d_out + 83886080;   // (16,5,1024,1024) f32 first

  char* ws = (char*)d_ws;
  ushort_t* adjb  = (ushort_t*)(ws);                       //  67108864 B (16,2,1024,1024)
  ushort_t* XT    = (ushort_t*)(ws + 67108864);            //   8388608 B (16,256,1024)
  ushort_t* W1T   = (ushort_t*)(ws + 75497472);            //    524288 B
  ushort_t* W2pT  = (ushort_t*)(ws + 76021760);            //    262144 B (2,128,512)
  ushort_t* Wf1T  = (ushort_t*)(ws + 76283904);            //    131072 B
  ushort_t* Wf2T  = (ushort_t*)(ws + 76414976);            //    131072 B
  ushort_t* AX    = (ushort_t*)(ws + 76546048);            //  16777216 B (16,2,1024,256)
  ushort_t* h1    = (ushort_t*)(ws + 93323264);            //  33554432 B
  ushort_t* sup2T = (ushort_t*)(ws + 126877696);           //   8388608 B (16,2,128,1024)
  ushort_t* glnb  = (ushort_t*)(ws + 135266304);           //   8388608 B
  ushort_t* tbuf  = (ushort_t*)(ws + 143654912);           //   8388608 B  (tot 152 MB)

  k_xt   <<<dim3(16, 4, 16), 256, 0, stream>>>(gnodes, XT);
  k_prepw<<<2048, 256, 0, stream>>>(Wg1, Wg2, Wf1, Wf2, W1T, W2pT, Wf1T, Wf2T);
  k_cast <<<81920, 256, 0, stream>>>(graph, adj_out, adjb);

  k_ax<<<dim3(2, 8, 32), 256, 0, stream>>>(adjb, XT, AX);
  k_h1<<<dim3(8, 8, 16), 256, 0, stream>>>(AX, W1T, bg1, h1);
  k_g3<<<dim3(2, 8, 32), 256, 0, stream>>>(W2pT, h1, sup2T);
  k_g4ln<<<dim3(32, 16), 256, 0, stream>>>(adjb, sup2T, bg2, gnodes, ln_a, ln_b, glnb);

  k_f1<<<dim3(2, 256), 256, 0, stream>>>(glnb, Wf1T, bf1, tbuf);
  k_f2<<<dim3(2, 256), 256, 0, stream>>>(tbuf, Wf2T, bf2, glnb, out);
}

// Round 6
// 664.959 us; speedup vs baseline: 1.1075x; 1.0428x over previous
//
#include <hip/hip_runtime.h>

typedef unsigned short ushort_t;
using short8  = __attribute__((ext_vector_type(8))) short;
using floatx4 = __attribute__((ext_vector_type(4))) float;

__device__ __forceinline__ ushort_t f2bf(float f) {
  unsigned int x = __builtin_bit_cast(unsigned int, f);
  x += 0x7fffu + ((x >> 16) & 1u);           // RNE
  return (ushort_t)(x >> 16);
}

__device__ __forceinline__ void gld16(const ushort_t* g, ushort_t* l) {
  __builtin_amdgcn_global_load_lds(
      (const __attribute__((address_space(1))) void*)(unsigned long long)(uintptr_t)g,
      (__attribute__((address_space(3))) void*)l, 16, 0, 0);
}

// ---------- 128x128 tile, 256 threads (4 waves 2x2), BK=64 ----------
// LDS rows are 64 cols = 8 x 16B chunks; stored chunk c holds global chunk c ^ (row&7).
template <typename F>
__device__ __forceinline__ void gemm_tile(const ushort_t* __restrict__ A, int lda,
                                          const ushort_t* __restrict__ BT, int ldb,
                                          int K, F epi) {
  __shared__ ushort_t As[128 * 64];
  __shared__ ushort_t Bs[128 * 64];

  const int tid  = threadIdx.x;
  const int wave = tid >> 6;
  const int lane = tid & 63;
  const int l15  = lane & 15;
  const int quad = lane >> 4;
  const int wm   = wave >> 1;
  const int wn   = wave & 1;

  const int srow8  = lane >> 3;
  const int schunk = lane & 7;
  const int gcol   = ((schunk ^ srow8) * 8);

  const ushort_t* gA = A  + (size_t)(wave * 32 + srow8) * lda + gcol;
  const ushort_t* gB = BT + (size_t)(wave * 32 + srow8) * ldb + gcol;
  ushort_t* lA = As + (wave * 32) * 64;
  ushort_t* lB = Bs + (wave * 32) * 64;

  floatx4 acc[4][4] = {};
  const int arow0 = (wm * 64 + l15) * 64;
  const int brow0 = (wn * 64 + l15) * 64;
  const int cx    = l15 & 7;

  for (int k0 = 0; k0 < K; k0 += 64) {
#pragma unroll
    for (int ci = 0; ci < 4; ci++) {
      gld16(gA + (size_t)(ci * 8) * lda, lA + ci * 512);
      gld16(gB + (size_t)(ci * 8) * ldb, lB + ci * 512);
    }
    gA += 64; gB += 64;
    __syncthreads();
#pragma unroll
    for (int ks = 0; ks < 2; ks++) {
      const int cs = ((ks * 4 + quad) ^ cx) * 8;
      short8 af[4], bfr[4];
#pragma unroll
      for (int i = 0; i < 4; i++) af[i]  = *(const short8*)(As + arow0 + i * 1024 + cs);
#pragma unroll
      for (int j = 0; j < 4; j++) bfr[j] = *(const short8*)(Bs + brow0 + j * 1024 + cs);
#pragma unroll
      for (int i = 0; i < 4; i++)
#pragma unroll
        for (int j = 0; j < 4; j++)
          acc[i][j] = __builtin_amdgcn_mfma_f32_16x16x32_bf16(af[i], bfr[j], acc[i][j], 0, 0, 0);
    }
    __syncthreads();
  }

#pragma unroll
  for (int i = 0; i < 4; i++)
#pragma unroll
    for (int j = 0; j < 4; j++)
#pragma unroll
      for (int r = 0; r < 4; r++)
        epi(wm * 64 + i * 16 + quad * 4 + r, wn * 64 + j * 16 + l15, acc[i][j][r]);
}

// ---------- 64x128 tile, 256 threads (4 waves 2x2, wave=32x64), BK=64 ----------
template <typename F>
__device__ __forceinline__ void gemm_tile64(const ushort_t* __restrict__ A, int lda,
                                            const ushort_t* __restrict__ BT, int ldb,
                                            int K, F epi) {
  __shared__ ushort_t As[64 * 64];    // 8 KB
  __shared__ ushort_t Bs[128 * 64];   // 16 KB

  const int tid  = threadIdx.x;
  const int wave = tid >> 6;
  const int lane = tid & 63;
  const int l15  = lane & 15;
  const int quad = lane >> 4;
  const int wm   = wave >> 1;
  const int wn   = wave & 1;

  const int srow8  = lane >> 3;
  const int schunk = lane & 7;
  const int gcol   = ((schunk ^ srow8) * 8);

  const ushort_t* gA = A  + (size_t)(wave * 16 + srow8) * lda + gcol;
  const ushort_t* gB = BT + (size_t)(wave * 32 + srow8) * ldb + gcol;
  ushort_t* lA = As + (wave * 16) * 64;
  ushort_t* lB = Bs + (wave * 32) * 64;

  floatx4 acc[2][4] = {};
  const int arow0 = (wm * 32 + l15) * 64;
  const int brow0 = (wn * 64 + l15) * 64;
  const int cx    = l15 & 7;

  for (int k0 = 0; k0 < K; k0 += 64) {
#pragma unroll
    for (int ci = 0; ci < 2; ci++)
      gld16(gA + (size_t)(ci * 8) * lda, lA + ci * 512);
#pragma unroll
    for (int ci = 0; ci < 4; ci++)
      gld16(gB + (size_t)(ci * 8) * ldb, lB + ci * 512);
    gA += 64; gB += 64;
    __syncthreads();
#pragma unroll
    for (int ks = 0; ks < 2; ks++) {
      const int cs = ((ks * 4 + quad) ^ cx) * 8;
      short8 af[2], bfr[4];
#pragma unroll
      for (int i = 0; i < 2; i++) af[i]  = *(const short8*)(As + arow0 + i * 1024 + cs);
#pragma unroll
      for (int j = 0; j < 4; j++) bfr[j] = *(const short8*)(Bs + brow0 + j * 1024 + cs);
#pragma unroll
      for (int i = 0; i < 2; i++)
#pragma unroll
        for (int j = 0; j < 4; j++)
          acc[i][j] = __builtin_amdgcn_mfma_f32_16x16x32_bf16(af[i], bfr[j], acc[i][j], 0, 0, 0);
    }
    __syncthreads();
  }

#pragma unroll
  for (int i = 0; i < 2; i++)
#pragma unroll
    for (int j = 0; j < 4; j++)
#pragma unroll
      for (int r = 0; r < 4; r++)
        epi(wm * 32 + i * 16 + quad * 4 + r, wn * 64 + j * 16 + l15, acc[i][j][r]);
}

// ---------------- merged prep kernel ----------------
// blocks [0, 81920): adj cast (f32 out + bf16 slices 1,4)
// blocks [81920, 82944): X transpose -> XT bf16
// blocks [82944, 84992): weight prep
__global__ __launch_bounds__(256) void k_prep(const int* __restrict__ graph,
                                              float* __restrict__ adj_out,
                                              ushort_t* __restrict__ adjb,
                                              const float* __restrict__ gn,
                                              ushort_t* __restrict__ XT,
                                              const float* __restrict__ Wg1, const float* __restrict__ Wg2,
                                              const float* __restrict__ Wf1, const float* __restrict__ Wf2,
                                              ushort_t* __restrict__ W1T, ushort_t* __restrict__ W2pT,
                                              ushort_t* __restrict__ Wf1T, ushort_t* __restrict__ Wf2T) {
  __shared__ float t[64][68];
  const int bid = blockIdx.x;
  if (bid < 81920) {
    const size_t i = (size_t)bid * 256 + threadIdx.x;   // int4 index
    int4 v = ((const int4*)graph)[i];
    float4 f = make_float4((float)v.x, (float)v.y, (float)v.z, (float)v.w);
    ((float4*)adj_out)[i] = f;
    const size_t e0 = i * 4;
    const unsigned sb = (unsigned)(e0 >> 20);
    const unsigned s = sb % 5u, b = sb / 5u;
    if (s == 1u || s == 4u) {
      const unsigned tt = (s == 4u) ? 1u : 0u;
      ushort4 h;
      h.x = f2bf(f.x); h.y = f2bf(f.y); h.z = f2bf(f.z); h.w = f2bf(f.w);
      *(ushort4*)(adjb + (((size_t)(b * 2 + tt)) << 20) + (e0 & 0xFFFFFu)) = h;
    }
  } else if (bid < 82944) {
    const int id = bid - 81920;
    const int kt = id & 15, dt = (id >> 4) & 3, b = id >> 6;
    const int r  = threadIdx.x >> 4;
    const int c4 = (threadIdx.x & 15) * 4;
#pragma unroll
    for (int rr = 0; rr < 4; rr++) {
      const int kl = rr * 16 + r;
      float4 v = *(const float4*)(gn + ((size_t)(b * 1024 + kt * 64 + kl)) * 256 + dt * 64 + c4);
      t[kl][c4] = v.x; t[kl][c4 + 1] = v.y; t[kl][c4 + 2] = v.z; t[kl][c4 + 3] = v.w;
    }
    __syncthreads();
#pragma unroll
    for (int rr = 0; rr < 4; rr++) {
      const int dl = rr * 16 + r;
      ushort4 h;
      h.x = f2bf(t[c4][dl]);     h.y = f2bf(t[c4 + 1][dl]);
      h.z = f2bf(t[c4 + 2][dl]); h.w = f2bf(t[c4 + 3][dl]);
      *(ushort4*)(XT + ((size_t)(b * 256 + dt * 64 + dl)) * 1024 + kt * 64 + c4) = h;
    }
  } else {
    const int i = (bid - 82944) * 256 + threadIdx.x;
    if (i < 262144) {
      const int fI = i >> 8, d = i & 255;
      const int h = fI >> 8, ff = fI & 255;
      W1T[i] = f2bf(Wg1[((h << 8) + d) * 256 + ff]);
    } else if (i < 393216) {
      const int j = i - 262144;                 // t(1) | e'(7) | k(9)
      const int tt = j >> 16, rem = j & 65535;
      const int ep = rem >> 9, k = rem & 511;
      const int hh = ep >> 6;
      const float v = ((k >> 8) == hh)
          ? Wg2[(((tt * 2 + hh) << 8) + (k & 255)) * 64 + (ep & 63)] : 0.f;
      W2pT[j] = f2bf(v);
    } else if (i < 458752) {
      const int j = i - 393216;
      const int n = j >> 8, k = j & 255;
      Wf1T[j] = f2bf(Wf1[k * 256 + n]);
    } else if (i < 524288) {
      const int j = i - 458752;
      const int n = j >> 8, k = j & 255;
      Wf2T[j] = f2bf(Wf2[k * 256 + n]);
    }
  }
}

// ---------------- GEMM step kernels ----------------

// AX[b,t] (1024k x 256d) = adj_t @ X   (BT = XT[b])  K=1024
__global__ __launch_bounds__(256) void k_ax(const ushort_t* __restrict__ adjb,
                                            const ushort_t* __restrict__ XT,
                                            ushort_t* __restrict__ AX) {
  const int nt = blockIdx.x, mt = blockIdx.y, bt = blockIdx.z;
  const int b = bt >> 1;
  const ushort_t* A  = adjb + ((size_t)bt << 20) + (size_t)mt * 128 * 1024;
  const ushort_t* BT = XT + ((size_t)b << 18) + (size_t)nt * 128 * 1024;
  ushort_t* C = AX + ((size_t)bt << 18);
  gemm_tile(A, 1024, BT, 1024, 1024, [&](int r, int c, float v) {
    C[(size_t)(mt * 128 + r) * 256 + nt * 128 + c] = f2bf(v);
  });
}

// h1 (1024k x 1024f) = relu(AX[b,t(h)] @ Wg1[h] + bg1)   (BT = W1T)  K=256
__global__ __launch_bounds__(256) void k_h1(const ushort_t* __restrict__ AX,
                                            const ushort_t* __restrict__ W1T,
                                            const float* __restrict__ bg1,
                                            ushort_t* __restrict__ h1) {
  const int nt = blockIdx.x, mt = blockIdx.y, b = blockIdx.z;
  const int t = nt >> 2;
  const ushort_t* A  = AX + ((size_t)(b * 2 + t) << 18) + (size_t)mt * 128 * 256;
  const ushort_t* BT = W1T + (size_t)nt * 128 * 256;
  ushort_t* C = h1 + ((size_t)b << 20);
  const float* bias = bg1 + nt * 128;
  gemm_tile(A, 256, BT, 256, 256, [&](int r, int c, float v) {
    C[(size_t)(mt * 128 + r) * 1024 + nt * 128 + c] = f2bf(fmaxf(v + bias[c], 0.f));
  });
}

// G3: sup2T[b,t](128e' x 1024k') = W2pT[t](128x512) @ h1[b][:, t*512:+512]^T   K=512
__global__ __launch_bounds__(256) void k_g3(const ushort_t* __restrict__ W2pT,
                                            const ushort_t* __restrict__ h1,
                                            ushort_t* __restrict__ sup2T) {
  const int mx = blockIdx.x, nt = blockIdx.y, bt = blockIdx.z;
  const int b = bt >> 1, t = bt & 1;
  const ushort_t* A  = W2pT + (size_t)t * 65536 + (size_t)mx * 64 * 512;
  const ushort_t* BT = h1 + ((size_t)b << 20) + (size_t)nt * 131072 + t * 512;
  ushort_t* C = sup2T + (size_t)bt * 131072;
  gemm_tile64(A, 512, BT, 1024, 512, [&](int r, int c, float v) {
    C[(size_t)(mx * 64 + r) * 1024 + nt * 128 + c] = f2bf(v);
  });
}

// ---------------- mega-tail: G4 + bias + LN + residual + FFN1 + relu + FFN2 + residual ----------------
// Block = 32 rows x 256 features, 4 waves side-by-side (wave wn -> cols wn*64..+64).
// Grid (32 mt, 16 b) = 512 blocks, 2 blocks/CU (73.5 KB LDS).
__global__ __launch_bounds__(256) void k_tail(const ushort_t* __restrict__ adjb,
                                              const ushort_t* __restrict__ sup2T,
                                              const float* __restrict__ bg2,
                                              const float* __restrict__ gn,
                                              const float* __restrict__ la,
                                              const float* __restrict__ lb,
                                              const ushort_t* __restrict__ Wf1T,
                                              const float* __restrict__ bf1,
                                              const ushort_t* __restrict__ Wf2T,
                                              const float* __restrict__ bf2,
                                              float* __restrict__ out) {
  __shared__ ushort_t As[64 * 64];             // 8 KB: rows 0..31 slice0, 32..63 slice1
  __shared__ ushort_t Bs[256 * 64];            // 32 KB: B staging (sup2T / Wf1T / Wf2T)
  __shared__ ushort_t Ps[32 * 256];            // 16 KB: gln bf16 (FFN GEMM1 A), swizzled
  __shared__ ushort_t Ts[32 * 256];            // 16 KB: relu intermediate, swizzled
  __shared__ float sred[4][32], qred[4][32];

  const int mt = blockIdx.x, b = blockIdx.y;
  const int tid = threadIdx.x, wave = tid >> 6, lane = tid & 63;
  const int l15 = lane & 15, quad = lane >> 4;
  const int wn = wave;
  const int tsel = wn >> 1;

  const int srow8 = lane >> 3, schunk = lane & 7;
  const int gcol = (schunk ^ srow8) * 8;

  // ---- phase 1: G4 (adj @ sup2), K=1024 ----
  const ushort_t* gA = adjb + ((size_t)(b * 2 + (wave >> 1)) << 20)
                     + (size_t)(mt * 32 + (wave & 1) * 16 + srow8) * 1024 + gcol;
  const ushort_t* gB = sup2T + (size_t)(b * 2 + (wave >> 1)) * 131072
                     + (size_t)((wave & 1) * 64 + srow8) * 1024 + gcol;
  ushort_t* lA = As + (wave * 16) * 64;
  ushort_t* lB = Bs + (wave * 64) * 64;

  floatx4 acc[2][4] = {};
  const int arow0 = (tsel * 32 + l15) * 64;
  const int brow0 = (wn * 64 + l15) * 64;
  const int cx = l15 & 7;

  for (int k0 = 0; k0 < 1024; k0 += 64) {
#pragma unroll
    for (int ci = 0; ci < 2; ci++)
      gld16(gA + (size_t)(ci * 8) * 1024, lA + ci * 512);
#pragma unroll
    for (int ci = 0; ci < 8; ci++)
      gld16(gB + (size_t)(ci * 8) * 1024, lB + ci * 512);
    gA += 64; gB += 64;
    __syncthreads();
#pragma unroll
    for (int ks = 0; ks < 2; ks++) {
      const int cs = ((ks * 4 + quad) ^ cx) * 8;
      short8 af[2], bfr[4];
#pragma unroll
      for (int i = 0; i < 2; i++) af[i]  = *(const short8*)(As + arow0 + i * 1024 + cs);
#pragma unroll
      for (int j = 0; j < 4; j++) bfr[j] = *(const short8*)(Bs + brow0 + j * 1024 + cs);
#pragma unroll
      for (int i = 0; i < 2; i++)
#pragma unroll
        for (int j = 0; j < 4; j++)
          acc[i][j] = __builtin_amdgcn_mfma_f32_16x16x32_bf16(af[i], bfr[j], acc[i][j], 0, 0, 0);
    }
    __syncthreads();
  }

  // ---- phase 2: bias + LN(ddof=1, eps on sd) + residual -> glnreg (f32) + Ps (bf16) ----
  float laj[4], lbj[4];
#pragma unroll
  for (int j = 0; j < 4; j++) {
    const int colg = wn * 64 + j * 16 + l15;
    const float bj = bg2[colg];
    laj[j] = la[colg]; lbj[j] = lb[colg];
#pragma unroll
    for (int i = 0; i < 2; i++)
#pragma unroll
      for (int r = 0; r < 4; r++) acc[i][j][r] += bj;
  }
#pragma unroll
  for (int i = 0; i < 2; i++)
#pragma unroll
    for (int r = 0; r < 4; r++) {
      float s = 0.f, q = 0.f;
#pragma unroll
      for (int j = 0; j < 4; j++) { const float v = acc[i][j][r]; s += v; q += v * v; }
#pragma unroll
      for (int m = 1; m < 16; m <<= 1) { s += __shfl_xor(s, m); q += __shfl_xor(q, m); }
      if (l15 == 0) {
        const int row = i * 16 + quad * 4 + r;
        sred[wn][row] = s; qred[wn][row] = q;
      }
    }
  __syncthreads();

  const size_t rowbase = (size_t)(b * 1024 + mt * 32);
  float glnreg[2][4][4];
#pragma unroll
  for (int i = 0; i < 2; i++)
#pragma unroll
    for (int r = 0; r < 4; r++) {
      const int row = i * 16 + quad * 4 + r;
      const float S = sred[0][row] + sred[1][row] + sred[2][row] + sred[3][row];
      const float Q = qred[0][row] + qred[1][row] + qred[2][row] + qred[3][row];
      const float mu = S * (1.f / 256.f);
      const float var = fmaxf((Q - S * mu) * (1.f / 255.f), 0.f);
      const float inv = 1.f / (sqrtf(var) + 1e-6f);
      const float* gnr = gn + (rowbase + row) * 256;
#pragma unroll
      for (int j = 0; j < 4; j++) {
        const int colg = wn * 64 + j * 16 + l15;
        const float g = laj[j] * (acc[i][j][r] - mu) * inv + lbj[j] + gnr[colg];
        glnreg[i][j][r] = g;
        // swizzled store: element (row,col) at row*256 + ((col>>3 ^ row)&31)*8 + (col&7)
        Ps[row * 256 + ((((colg >> 3) ^ row) & 31) << 3) + (colg & 7)] = f2bf(g);
      }
    }
  __syncthreads();

  // ---- phase 3: FFN GEMM1: t = relu(gln @ Wf1 + bf1), K=256, A from Ps ----
  floatx4 acc2[2][4] = {};
  for (int k0 = 0; k0 < 256; k0 += 64) {
#pragma unroll
    for (int ci = 0; ci < 8; ci++)
      gld16(Wf1T + (size_t)(wave * 64 + ci * 8 + srow8) * 256 + k0 + gcol,
            Bs + (wave * 64 + ci * 8) * 64);
    __syncthreads();
#pragma unroll
    for (int ks = 0; ks < 2; ks++) {
      const int c32 = (k0 >> 3) + ks * 4 + quad;      // global 8-el k-chunk
      const int cs = ((ks * 4 + quad) ^ cx) * 8;
      short8 af[2], bfr[4];
#pragma unroll
      for (int i = 0; i < 2; i++) {
        const int row = i * 16 + l15;
        af[i] = *(const short8*)(Ps + row * 256 + (((c32 ^ row) & 31) << 3));
      }
#pragma unroll
      for (int j = 0; j < 4; j++) bfr[j] = *(const short8*)(Bs + brow0 + j * 1024 + cs);
#pragma unroll
      for (int i = 0; i < 2; i++)
#pragma unroll
        for (int j = 0; j < 4; j++)
          acc2[i][j] = __builtin_amdgcn_mfma_f32_16x16x32_bf16(af[i], bfr[j], acc2[i][j], 0, 0, 0);
    }
    __syncthreads();
  }

  // ---- phase 4: relu + bf1 -> Ts ----
#pragma unroll
  for (int j = 0; j < 4; j++) {
    const int colg = wn * 64 + j * 16 + l15;
    const float bj = bf1[colg];
#pragma unroll
    for (int i = 0; i < 2; i++)
#pragma unroll
      for (int r = 0; r < 4; r++) {
        const int row = i * 16 + quad * 4 + r;
        const float v = fmaxf(acc2[i][j][r] + bj, 0.f);
        Ts[row * 256 + ((((colg >> 3) ^ row) & 31) << 3) + (colg & 7)] = f2bf(v);
      }
  }
  __syncthreads();

  // ---- phase 5: FFN GEMM2: out = t @ Wf2 + bf2 + gln, K=256, A from Ts ----
  floatx4 acc3[2][4] = {};
  for (int k0 = 0; k0 < 256; k0 += 64) {
#pragma unroll
    for (int ci = 0; ci < 8; ci++)
      gld16(Wf2T + (size_t)(wave * 64 + ci * 8 + srow8) * 256 + k0 + gcol,
            Bs + (wave * 64 + ci * 8) * 64);
    __syncthreads();
#pragma unroll
    for (int ks = 0; ks < 2; ks++) {
      const int c32 = (k0 >> 3) + ks * 4 + quad;
      const int cs = ((ks * 4 + quad) ^ cx) * 8;
      short8 af[2], bfr[4];
#pragma unroll
      for (int i = 0; i < 2; i++) {
        const int row = i * 16 + l15;
        af[i] = *(const short8*)(Ts + row * 256 + (((c32 ^ row) & 31) << 3));
      }
#pragma unroll
      for (int j = 0; j < 4; j++) bfr[j] = *(const short8*)(Bs + brow0 + j * 1024 + cs);
#pragma unroll
      for (int i = 0; i < 2; i++)
#pragma unroll
        for (int j = 0; j < 4; j++)
          acc3[i][j] = __builtin_amdgcn_mfma_f32_16x16x32_bf16(af[i], bfr[j], acc3[i][j], 0, 0, 0);
    }
    __syncthreads();
  }

  // ---- phase 6: + bf2 + gln residual (f32), write out ----
#pragma unroll
  for (int j = 0; j < 4; j++) {
    const int colg = wn * 64 + j * 16 + l15;
    const float bj = bf2[colg];
#pragma unroll
    for (int i = 0; i < 2; i++)
#pragma unroll
      for (int r = 0; r < 4; r++) {
        const int row = i * 16 + quad * 4 + r;
        out[(rowbase + row) * 256 + colg] = acc3[i][j][r] + bj + glnreg[i][j][r];
      }
  }
}

extern "C" void kernel_launch(void* const* d_in, const int* in_sizes, int n_in,
                              void* d_out, int out_size, void* d_ws, size_t ws_size,
                              hipStream_t stream) {
  const float* gnodes = (const float*)d_in[0];
  const int*   graph  = (const int*)d_in[1];
  const float* Wg1 = (const float*)d_in[2];
  const float* bg1 = (const float*)d_in[3];
  const float* Wg2 = (const float*)d_in[4];
  const float* bg2 = (const float*)d_in[5];
  const float* Wf1 = (const float*)d_in[6];
  const float* bf1 = (const float*)d_in[7];
  const float* Wf2 = (const float*)d_in[8];
  const float* bf2 = (const float*)d_in[9];
  const float* ln_a = (const float*)d_in[10];
  const float* ln_b = (const float*)d_in[11];

  float* adj_out = (float*)d_out;
  float* out     = (float*)d_out + 83886080;   // (16,5,1024,1024) f32 first

  char* ws = (char*)d_ws;
  ushort_t* adjb  = (ushort_t*)(ws);                       //  67108864 B (16,2,1024,1024)
  ushort_t* XT    = (ushort_t*)(ws + 67108864);            //   8388608 B (16,256,1024)
  ushort_t* W1T   = (ushort_t*)(ws + 75497472);            //    524288 B
  ushort_t* W2pT  = (ushort_t*)(ws + 76021760);            //    262144 B (2,128,512)
  ushort_t* Wf1T  = (ushort_t*)(ws + 76283904);            //    131072 B
  ushort_t* Wf2T  = (ushort_t*)(ws + 76414976);            //    131072 B
  ushort_t* AX    = (ushort_t*)(ws + 76546048);            //  16777216 B (16,2,1024,256)
  ushort_t* h1    = (ushort_t*)(ws + 93323264);            //  33554432 B
  ushort_t* sup2T = (ushort_t*)(ws + 126877696);           //   8388608 B (16,2,128,1024)

  k_prep<<<84992, 256, 0, stream>>>(graph, adj_out, adjb, gnodes, XT,
                                    Wg1, Wg2, Wf1, Wf2, W1T, W2pT, Wf1T, Wf2T);

  k_ax<<<dim3(2, 8, 32), 256, 0, stream>>>(adjb, XT, AX);
  k_h1<<<dim3(8, 8, 16), 256, 0, stream>>>(AX, W1T, bg1, h1);
  k_g3<<<dim3(2, 8, 32), 256, 0, stream>>>(W2pT, h1, sup2T);
  k_tail<<<dim3(32, 16), 256, 0, stream>>>(adjb, sup2T, bg2, gnodes, ln_a, ln_b,
                                           Wf1T, bf1, Wf2T, bf2, out);
}

// Round 7
// 657.590 us; speedup vs baseline: 1.1199x; 1.0112x over previous
//
#include <hip/hip_runtime.h>

typedef unsigned short ushort_t;
using short8  = __attribute__((ext_vector_type(8))) short;
using floatx4 = __attribute__((ext_vector_type(4))) float;

__device__ __forceinline__ ushort_t f2bf(float f) {
  unsigned int x = __builtin_bit_cast(unsigned int, f);
  x += 0x7fffu + ((x >> 16) & 1u);           // RNE
  return (ushort_t)(x >> 16);
}

__device__ __forceinline__ void gld16(const ushort_t* g, ushort_t* l) {
  __builtin_amdgcn_global_load_lds(
      (const __attribute__((address_space(1))) void*)(unsigned long long)(uintptr_t)g,
      (__attribute__((address_space(3))) void*)l, 16, 0, 0);
}

// ---------------- merged prep kernel ----------------
// blocks [0, 81920): adj cast (f32 out + bf16 slices 1,4)
// blocks [81920, 82944): X transpose -> XT bf16
// blocks [82944, 84992): weight prep
__global__ __launch_bounds__(256) void k_prep(const int* __restrict__ graph,
                                              float* __restrict__ adj_out,
                                              ushort_t* __restrict__ adjb,
                                              const float* __restrict__ gn,
                                              ushort_t* __restrict__ XT,
                                              const float* __restrict__ Wg1, const float* __restrict__ Wg2,
                                              const float* __restrict__ Wf1, const float* __restrict__ Wf2,
                                              ushort_t* __restrict__ W1T, ushort_t* __restrict__ W2pT,
                                              ushort_t* __restrict__ Wf1T, ushort_t* __restrict__ Wf2T) {
  __shared__ float t[64][68];
  const int bid = blockIdx.x;
  if (bid < 81920) {
    const size_t i = (size_t)bid * 256 + threadIdx.x;   // int4 index
    int4 v = ((const int4*)graph)[i];
    float4 f = make_float4((float)v.x, (float)v.y, (float)v.z, (float)v.w);
    ((float4*)adj_out)[i] = f;
    const size_t e0 = i * 4;
    const unsigned sb = (unsigned)(e0 >> 20);
    const unsigned s = sb % 5u, b = sb / 5u;
    if (s == 1u || s == 4u) {
      const unsigned tt = (s == 4u) ? 1u : 0u;
      ushort4 h;
      h.x = f2bf(f.x); h.y = f2bf(f.y); h.z = f2bf(f.z); h.w = f2bf(f.w);
      *(ushort4*)(adjb + (((size_t)(b * 2 + tt)) << 20) + (e0 & 0xFFFFFu)) = h;
    }
  } else if (bid < 82944) {
    const int id = bid - 81920;
    const int kt = id & 15, dt = (id >> 4) & 3, b = id >> 6;
    const int r  = threadIdx.x >> 4;
    const int c4 = (threadIdx.x & 15) * 4;
#pragma unroll
    for (int rr = 0; rr < 4; rr++) {
      const int kl = rr * 16 + r;
      float4 v = *(const float4*)(gn + ((size_t)(b * 1024 + kt * 64 + kl)) * 256 + dt * 64 + c4);
      t[kl][c4] = v.x; t[kl][c4 + 1] = v.y; t[kl][c4 + 2] = v.z; t[kl][c4 + 3] = v.w;
    }
    __syncthreads();
#pragma unroll
    for (int rr = 0; rr < 4; rr++) {
      const int dl = rr * 16 + r;
      ushort4 h;
      h.x = f2bf(t[c4][dl]);     h.y = f2bf(t[c4 + 1][dl]);
      h.z = f2bf(t[c4 + 2][dl]); h.w = f2bf(t[c4 + 3][dl]);
      *(ushort4*)(XT + ((size_t)(b * 256 + dt * 64 + dl)) * 1024 + kt * 64 + c4) = h;
    }
  } else {
    const int i = (bid - 82944) * 256 + threadIdx.x;
    if (i < 262144) {
      const int fI = i >> 8, d = i & 255;
      const int h = fI >> 8, ff = fI & 255;
      W1T[i] = f2bf(Wg1[((h << 8) + d) * 256 + ff]);
    } else if (i < 393216) {
      const int j = i - 262144;                 // t(1) | e'(7) | k(9)
      const int tt = j >> 16, rem = j & 65535;
      const int ep = rem >> 9, k = rem & 511;
      const int hh = ep >> 6;
      const float v = ((k >> 8) == hh)
          ? Wg2[(((tt * 2 + hh) << 8) + (k & 255)) * 64 + (ep & 63)] : 0.f;
      W2pT[j] = f2bf(v);
    } else if (i < 458752) {
      const int j = i - 393216;
      const int n = j >> 8, k = j & 255;
      Wf1T[j] = f2bf(Wf1[k * 256 + n]);
    } else if (i < 524288) {
      const int j = i - 458752;
      const int n = j >> 8, k = j & 255;
      Wf2T[j] = f2bf(Wf2[k * 256 + n]);
    }
  }
}

// ---------------- fused mid-chain: AX = adj@X -> h1 = relu(AX@W1+b) -> sup2 = W2p@h1^T ----------------
// Block = (mt: 64 adj-rows, bt = b*2+t). Grid (16,32) = 512 blocks, 2 blocks/CU (72 KB LDS).
// AX and h1 live entirely in LDS/registers; only sup2T (8 MB) goes to global.
__global__ __launch_bounds__(256) void k_mid(const ushort_t* __restrict__ adjb,
                                             const ushort_t* __restrict__ XT,
                                             const ushort_t* __restrict__ W1T,
                                             const float* __restrict__ bg1,
                                             const ushort_t* __restrict__ W2pT,
                                             ushort_t* __restrict__ sup2T) {
  __shared__ ushort_t As[64 * 64];     // 8 KB: phase-1 A staging (adj rows)
  __shared__ ushort_t Bs[256 * 64];    // 32 KB: XT staging / W1T staging / W2pT staging (+Hs in 2nd half)
  __shared__ ushort_t AXs[64 * 256];   // 32 KB: AX bf16, swizzled (A-operand for phase 3)
  ushort_t* Hs = Bs + 8192;            // 16 KB region: h1 chunk 64x128, swizzled (B-operand for phase 4)

  const int mt = blockIdx.x, bt = blockIdx.y;
  const int b = bt >> 1, t = bt & 1;
  const int tid = threadIdx.x, wave = tid >> 6, lane = tid & 63;
  const int l15 = lane & 15, quad = lane >> 4;
  const int wm = wave >> 1, wn = wave & 1;
  const int srow8 = lane >> 3, schunk = lane & 7;
  const int gcol = (schunk ^ srow8) * 8;
  const int cx = l15 & 7;

  // ---- phase 1: AX(64x256) = adj[rows mt*64..+64] @ X, K=1024; wave-tile 32x128 ----
  const ushort_t* gA = adjb + ((size_t)bt << 20) + (size_t)(mt * 64 + wave * 16 + srow8) * 1024 + gcol;
  const ushort_t* gB = XT + ((size_t)b << 18) + (size_t)(wave * 64 + srow8) * 1024 + gcol;
  ushort_t* lA = As + (wave * 16) * 64;
  ushort_t* lB = Bs + (wave * 64) * 64;

  floatx4 acc1[2][8] = {};
  const int arow1 = (wm * 32 + l15) * 64;
  const int brow1 = (wn * 128 + l15) * 64;

  for (int k0 = 0; k0 < 1024; k0 += 64) {
#pragma unroll
    for (int ci = 0; ci < 2; ci++) gld16(gA + (size_t)(ci * 8) * 1024, lA + ci * 512);
#pragma unroll
    for (int ci = 0; ci < 8; ci++) gld16(gB + (size_t)(ci * 8) * 1024, lB + ci * 512);
    gA += 64; gB += 64;
    __syncthreads();
#pragma unroll
    for (int ks = 0; ks < 2; ks++) {
      const int cs = ((ks * 4 + quad) ^ cx) * 8;
      short8 af[2], bfr[8];
#pragma unroll
      for (int i = 0; i < 2; i++) af[i]  = *(const short8*)(As + arow1 + i * 1024 + cs);
#pragma unroll
      for (int j = 0; j < 8; j++) bfr[j] = *(const short8*)(Bs + brow1 + j * 1024 + cs);
#pragma unroll
      for (int i = 0; i < 2; i++)
#pragma unroll
        for (int j = 0; j < 8; j++)
          acc1[i][j] = __builtin_amdgcn_mfma_f32_16x16x32_bf16(af[i], bfr[j], acc1[i][j], 0, 0, 0);
    }
    __syncthreads();
  }

  // ---- phase 2: AX -> AXs (bf16, swizzled: (row,d) at row*256 + (((d>>3)^row)&31)*8 + (d&7)) ----
#pragma unroll
  for (int i = 0; i < 2; i++)
#pragma unroll
    for (int j = 0; j < 8; j++)
#pragma unroll
      for (int r = 0; r < 4; r++) {
        const int row = wm * 32 + i * 16 + quad * 4 + r;
        const int d   = wn * 128 + j * 16 + l15;
        AXs[row * 256 + ((((d >> 3) ^ row) & 31) << 3) + (d & 7)] = f2bf(acc1[i][j][r]);
      }
  __syncthreads();

  floatx4 acc4[4][2] = {};   // sup2: 128 e' x 64 k' (wave-tile 64x32), persists over nn

#pragma unroll 1
  for (int nn = 0; nn < 4; nn++) {
    const int fg = t * 512 + nn * 128;   // global feature base of this chunk

    // ---- phase 3: h1chunk(64 x 128) = relu(AXs @ W1T[fg..fg+128]^T + bg1), K=256; wave 32x64 ----
    floatx4 acc3[2][4] = {};
    for (int k0 = 0; k0 < 256; k0 += 64) {
#pragma unroll
      for (int ci = 0; ci < 4; ci++)
        gld16(W1T + (size_t)(fg + wave * 32 + ci * 8 + srow8) * 256 + k0 + gcol,
              Bs + (wave * 32 + ci * 8) * 64);
      __syncthreads();
#pragma unroll
      for (int ks = 0; ks < 2; ks++) {
        const int c32 = (k0 >> 3) + ks * 4 + quad;
        const int cs = ((ks * 4 + quad) ^ cx) * 8;
        short8 af[2], bfr[4];
#pragma unroll
        for (int i = 0; i < 2; i++) {
          const int row = wm * 32 + i * 16 + l15;
          af[i] = *(const short8*)(AXs + row * 256 + (((c32 ^ row) & 31) << 3));
        }
#pragma unroll
        for (int j = 0; j < 4; j++)
          bfr[j] = *(const short8*)(Bs + (wn * 64 + j * 16 + l15) * 64 + cs);
#pragma unroll
        for (int i = 0; i < 2; i++)
#pragma unroll
          for (int j = 0; j < 4; j++)
            acc3[i][j] = __builtin_amdgcn_mfma_f32_16x16x32_bf16(af[i], bfr[j], acc3[i][j], 0, 0, 0);
      }
      __syncthreads();
    }

    // relu + bg1 -> Hs (64 x 128, swizzled mod 16)
#pragma unroll
    for (int j = 0; j < 4; j++) {
      const int fl = wn * 64 + j * 16 + l15;          // 0..127
      const float bj = bg1[fg + fl];
#pragma unroll
      for (int i = 0; i < 2; i++)
#pragma unroll
        for (int r = 0; r < 4; r++) {
          const int row = wm * 32 + i * 16 + quad * 4 + r;
          const float v = fmaxf(acc3[i][j][r] + bj, 0.f);
          Hs[row * 128 + ((((fl >> 3) ^ row) & 15) << 3) + (fl & 7)] = f2bf(v);
        }
    }
    __syncthreads();

    // ---- phase 4: acc4 += W2pT[t][:, nn*128..+128] @ h1chunk^T, K=128; wave 64x32 ----
    for (int k0 = 0; k0 < 128; k0 += 64) {
#pragma unroll
      for (int ci = 0; ci < 4; ci++)
        gld16(W2pT + (size_t)t * 65536 + (size_t)(wave * 32 + ci * 8 + srow8) * 512 + nn * 128 + k0 + gcol,
              Bs + (wave * 32 + ci * 8) * 64);
      __syncthreads();
#pragma unroll
      for (int ks = 0; ks < 2; ks++) {
        const int c32h = (k0 >> 3) + ks * 4 + quad;   // fl 8-chunk 0..15
        const int cs = ((ks * 4 + quad) ^ cx) * 8;
        short8 af[4], bfr[2];
#pragma unroll
        for (int i = 0; i < 4; i++)
          af[i] = *(const short8*)(Bs + (wm * 64 + i * 16 + l15) * 64 + cs);
#pragma unroll
        for (int j = 0; j < 2; j++) {
          const int row = wn * 32 + j * 16 + l15;
          bfr[j] = *(const short8*)(Hs + row * 128 + (((c32h ^ row) & 15) << 3));
        }
#pragma unroll
        for (int i = 0; i < 4; i++)
#pragma unroll
          for (int j = 0; j < 2; j++)
            acc4[i][j] = __builtin_amdgcn_mfma_f32_16x16x32_bf16(af[i], bfr[j], acc4[i][j], 0, 0, 0);
      }
      __syncthreads();
    }
  }

  // ---- phase 5: write sup2T[b,t] (128 e' x cols mt*64..+64) ----
#pragma unroll
  for (int i = 0; i < 4; i++)
#pragma unroll
    for (int j = 0; j < 2; j++)
#pragma unroll
      for (int r = 0; r < 4; r++) {
        const int ep = wm * 64 + i * 16 + quad * 4 + r;
        const int kp = mt * 64 + wn * 32 + j * 16 + l15;
        sup2T[(size_t)bt * 131072 + (size_t)ep * 1024 + kp] = f2bf(acc4[i][j][r]);
      }
}

// ---------------- mega-tail: G4 + bias + LN + residual + FFN1 + relu + FFN2 + residual ----------------
// Block = 32 rows x 256 features, 4 waves side-by-side. Grid (32 mt, 16 b) = 512 blocks.
__global__ __launch_bounds__(256) void k_tail(const ushort_t* __restrict__ adjb,
                                              const ushort_t* __restrict__ sup2T,
                                              const float* __restrict__ bg2,
                                              const float* __restrict__ gn,
                                              const float* __restrict__ la,
                                              const float* __restrict__ lb,
                                              const ushort_t* __restrict__ Wf1T,
                                              const float* __restrict__ bf1,
                                              const ushort_t* __restrict__ Wf2T,
                                              const float* __restrict__ bf2,
                                              float* __restrict__ out) {
  __shared__ ushort_t As[64 * 64];             // 8 KB: rows 0..31 slice0, 32..63 slice1
  __shared__ ushort_t Bs[256 * 64];            // 32 KB: B staging (sup2T / Wf1T / Wf2T)
  __shared__ ushort_t Ps[32 * 256];            // 16 KB: gln bf16 (FFN GEMM1 A), swizzled
  __shared__ ushort_t Ts[32 * 256];            // 16 KB: relu intermediate, swizzled
  __shared__ float sred[4][32], qred[4][32];

  const int mt = blockIdx.x, b = blockIdx.y;
  const int tid = threadIdx.x, wave = tid >> 6, lane = tid & 63;
  const int l15 = lane & 15, quad = lane >> 4;
  const int wn = wave;
  const int tsel = wn >> 1;

  const int srow8 = lane >> 3, schunk = lane & 7;
  const int gcol = (schunk ^ srow8) * 8;

  // ---- phase 1: G4 (adj @ sup2), K=1024 ----
  const ushort_t* gA = adjb + ((size_t)(b * 2 + (wave >> 1)) << 20)
                     + (size_t)(mt * 32 + (wave & 1) * 16 + srow8) * 1024 + gcol;
  const ushort_t* gB = sup2T + (size_t)(b * 2 + (wave >> 1)) * 131072
                     + (size_t)((wave & 1) * 64 + srow8) * 1024 + gcol;
  ushort_t* lA = As + (wave * 16) * 64;
  ushort_t* lB = Bs + (wave * 64) * 64;

  floatx4 acc[2][4] = {};
  const int arow0 = (tsel * 32 + l15) * 64;
  const int brow0 = (wn * 64 + l15) * 64;
  const int cx = l15 & 7;

  for (int k0 = 0; k0 < 1024; k0 += 64) {
#pragma unroll
    for (int ci = 0; ci < 2; ci++)
      gld16(gA + (size_t)(ci * 8) * 1024, lA + ci * 512);
#pragma unroll
    for (int ci = 0; ci < 8; ci++)
      gld16(gB + (size_t)(ci * 8) * 1024, lB + ci * 512);
    gA += 64; gB += 64;
    __syncthreads();
#pragma unroll
    for (int ks = 0; ks < 2; ks++) {
      const int cs = ((ks * 4 + quad) ^ cx) * 8;
      short8 af[2], bfr[4];
#pragma unroll
      for (int i = 0; i < 2; i++) af[i]  = *(const short8*)(As + arow0 + i * 1024 + cs);
#pragma unroll
      for (int j = 0; j < 4; j++) bfr[j] = *(const short8*)(Bs + brow0 + j * 1024 + cs);
#pragma unroll
      for (int i = 0; i < 2; i++)
#pragma unroll
        for (int j = 0; j < 4; j++)
          acc[i][j] = __builtin_amdgcn_mfma_f32_16x16x32_bf16(af[i], bfr[j], acc[i][j], 0, 0, 0);
    }
    __syncthreads();
  }

  // ---- phase 2: bias + LN(ddof=1, eps on sd) + residual -> glnreg (f32) + Ps (bf16) ----
  float laj[4], lbj[4];
#pragma unroll
  for (int j = 0; j < 4; j++) {
    const int colg = wn * 64 + j * 16 + l15;
    const float bj = bg2[colg];
    laj[j] = la[colg]; lbj[j] = lb[colg];
#pragma unroll
    for (int i = 0; i < 2; i++)
#pragma unroll
      for (int r = 0; r < 4; r++) acc[i][j][r] += bj;
  }
#pragma unroll
  for (int i = 0; i < 2; i++)
#pragma unroll
    for (int r = 0; r < 4; r++) {
      float s = 0.f, q = 0.f;
#pragma unroll
      for (int j = 0; j < 4; j++) { const float v = acc[i][j][r]; s += v; q += v * v; }
#pragma unroll
      for (int m = 1; m < 16; m <<= 1) { s += __shfl_xor(s, m); q += __shfl_xor(q, m); }
      if (l15 == 0) {
        const int row = i * 16 + quad * 4 + r;
        sred[wn][row] = s; qred[wn][row] = q;
      }
    }
  __syncthreads();

  const size_t rowbase = (size_t)(b * 1024 + mt * 32);
  float glnreg[2][4][4];
#pragma unroll
  for (int i = 0; i < 2; i++)
#pragma unroll
    for (int r = 0; r < 4; r++) {
      const int row = i * 16 + quad * 4 + r;
      const float S = sred[0][row] + sred[1][row] + sred[2][row] + sred[3][row];
      const float Q = qred[0][row] + qred[1][row] + qred[2][row] + qred[3][row];
      const float mu = S * (1.f / 256.f);
      const float var = fmaxf((Q - S * mu) * (1.f / 255.f), 0.f);
      const float inv = 1.f / (sqrtf(var) + 1e-6f);
      const float* gnr = gn + (rowbase + row) * 256;
#pragma unroll
      for (int j = 0; j < 4; j++) {
        const int colg = wn * 64 + j * 16 + l15;
        const float g = laj[j] * (acc[i][j][r] - mu) * inv + lbj[j] + gnr[colg];
        glnreg[i][j][r] = g;
        Ps[row * 256 + ((((colg >> 3) ^ row) & 31) << 3) + (colg & 7)] = f2bf(g);
      }
    }
  __syncthreads();

  // ---- phase 3: FFN GEMM1: t = relu(gln @ Wf1 + bf1), K=256, A from Ps ----
  floatx4 acc2[2][4] = {};
  for (int k0 = 0; k0 < 256; k0 += 64) {
#pragma unroll
    for (int ci = 0; ci < 8; ci++)
      gld16(Wf1T + (size_t)(wave * 64 + ci * 8 + srow8) * 256 + k0 + gcol,
            Bs + (wave * 64 + ci * 8) * 64);
    __syncthreads();
#pragma unroll
    for (int ks = 0; ks < 2; ks++) {
      const int c32 = (k0 >> 3) + ks * 4 + quad;
      const int cs = ((ks * 4 + quad) ^ cx) * 8;
      short8 af[2], bfr[4];
#pragma unroll
      for (int i = 0; i < 2; i++) {
        const int row = i * 16 + l15;
        af[i] = *(const short8*)(Ps + row * 256 + (((c32 ^ row) & 31) << 3));
      }
#pragma unroll
      for (int j = 0; j < 4; j++) bfr[j] = *(const short8*)(Bs + brow0 + j * 1024 + cs);
#pragma unroll
      for (int i = 0; i < 2; i++)
#pragma unroll
        for (int j = 0; j < 4; j++)
          acc2[i][j] = __builtin_amdgcn_mfma_f32_16x16x32_bf16(af[i], bfr[j], acc2[i][j], 0, 0, 0);
    }
    __syncthreads();
  }

  // ---- phase 4: relu + bf1 -> Ts ----
#pragma unroll
  for (int j = 0; j < 4; j++) {
    const int colg = wn * 64 + j * 16 + l15;
    const float bj = bf1[colg];
#pragma unroll
    for (int i = 0; i < 2; i++)
#pragma unroll
      for (int r = 0; r < 4; r++) {
        const int row = i * 16 + quad * 4 + r;
        const float v = fmaxf(acc2[i][j][r] + bj, 0.f);
        Ts[row * 256 + ((((colg >> 3) ^ row) & 31) << 3) + (colg & 7)] = f2bf(v);
      }
  }
  __syncthreads();

  // ---- phase 5: FFN GEMM2: out = t @ Wf2 + bf2 + gln, K=256, A from Ts ----
  floatx4 acc3[2][4] = {};
  for (int k0 = 0; k0 < 256; k0 += 64) {
#pragma unroll
    for (int ci = 0; ci < 8; ci++)
      gld16(Wf2T + (size_t)(wave * 64 + ci * 8 + srow8) * 256 + k0 + gcol,
            Bs + (wave * 64 + ci * 8) * 64);
    __syncthreads();
#pragma unroll
    for (int ks = 0; ks < 2; ks++) {
      const int c32 = (k0 >> 3) + ks * 4 + quad;
      const int cs = ((ks * 4 + quad) ^ cx) * 8;
      short8 af[2], bfr[4];
#pragma unroll
      for (int i = 0; i < 2; i++) {
        const int row = i * 16 + l15;
        af[i] = *(const short8*)(Ts + row * 256 + (((c32 ^ row) & 31) << 3));
      }
#pragma unroll
      for (int j = 0; j < 4; j++) bfr[j] = *(const short8*)(Bs + brow0 + j * 1024 + cs);
#pragma unroll
      for (int i = 0; i < 2; i++)
#pragma unroll
        for (int j = 0; j < 4; j++)
          acc3[i][j] = __builtin_amdgcn_mfma_f32_16x16x32_bf16(af[i], bfr[j], acc3[i][j], 0, 0, 0);
    }
    __syncthreads();
  }

  // ---- phase 6: + bf2 + gln residual (f32), write out ----
#pragma unroll
  for (int j = 0; j < 4; j++) {
    const int colg = wn * 64 + j * 16 + l15;
    const float bj = bf2[colg];
#pragma unroll
    for (int i = 0; i < 2; i++)
#pragma unroll
      for (int r = 0; r < 4; r++) {
        const int row = i * 16 + quad * 4 + r;
        out[(rowbase + row) * 256 + colg] = acc3[i][j][r] + bj + glnreg[i][j][r];
      }
  }
}

extern "C" void kernel_launch(void* const* d_in, const int* in_sizes, int n_in,
                              void* d_out, int out_size, void* d_ws, size_t ws_size,
                              hipStream_t stream) {
  const float* gnodes = (const float*)d_in[0];
  const int*   graph  = (const int*)d_in[1];
  const float* Wg1 = (const float*)d_in[2];
  const float* bg1 = (const float*)d_in[3];
  const float* Wg2 = (const float*)d_in[4];
  const float* bg2 = (const float*)d_in[5];
  const float* Wf1 = (const float*)d_in[6];
  const float* bf1 = (const float*)d_in[7];
  const float* Wf2 = (const float*)d_in[8];
  const float* bf2 = (const float*)d_in[9];
  const float* ln_a = (const float*)d_in[10];
  const float* ln_b = (const float*)d_in[11];

  float* adj_out = (float*)d_out;
  float* out     = (float*)d_out + 83886080;   // (16,5,1024,1024) f32 first

  char* ws = (char*)d_ws;
  ushort_t* adjb  = (ushort_t*)(ws);                       //  67108864 B (16,2,1024,1024)
  ushort_t* XT    = (ushort_t*)(ws + 67108864);            //   8388608 B (16,256,1024)
  ushort_t* W1T   = (ushort_t*)(ws + 75497472);            //    524288 B
  ushort_t* W2pT  = (ushort_t*)(ws + 76021760);            //    262144 B (2,128,512)
  ushort_t* Wf1T  = (ushort_t*)(ws + 76283904);            //    131072 B
  ushort_t* Wf2T  = (ushort_t*)(ws + 76414976);            //    131072 B
  ushort_t* sup2T = (ushort_t*)(ws + 76546048);            //   8388608 B (16,2,128,1024)

  k_prep<<<84992, 256, 0, stream>>>(graph, adj_out, adjb, gnodes, XT,
                                    Wg1, Wg2, Wf1, Wf2, W1T, W2pT, Wf1T, Wf2T);

  k_mid<<<dim3(16, 32), 256, 0, stream>>>(adjb, XT, W1T, bg1, W2pT, sup2T);

  k_tail<<<dim3(32, 16), 256, 0, stream>>>(adjb, sup2T, bg2, gnodes, ln_a, ln_b,
                                           Wf1T, bf1, Wf2T, bf2, out);
}